// Round 7
// baseline (271.759 us; speedup 1.0000x reference)
//
#include <hip/hip_runtime.h>

#define NT 1024      // N_TOPICS
#define TD 128       // TOPIC_DIM
#define HID 512      // HIDDEN
#define NH 8         // N_HEADS
#define HD 64        // HEAD_DIM
#define NB 8         // BATCH

typedef unsigned short us;
typedef short bf16x8 __attribute__((ext_vector_type(8)));
typedef float f32x4 __attribute__((ext_vector_type(4)));

__device__ __forceinline__ us f2bf(float x) {
    unsigned int u = __float_as_uint(x);
    return (us)((u + 0x7FFFu + ((u >> 16) & 1u)) >> 16);
}
__device__ __forceinline__ float bf2f(us s) {
    return __uint_as_float(((unsigned int)s) << 16);
}

// ============ kprep: kmax (0-1023) | knode0 (1024-1279, 4 rows/blk) | kcvt (1280-1407) ==
__global__ __launch_bounds__(256) void kprep(const float* __restrict__ tm, float* __restrict__ part,
                                             const float* __restrict__ emb, const float* __restrict__ sW,
                                             const float* __restrict__ sb, us* __restrict__ node0b,
                                             const float* __restrict__ gW, us* __restrict__ Wt) {
    __shared__ __align__(16) float smf[8768];   // 35 KB, shared by all branches
    int bx = blockIdx.x, t = threadIdx.x;
    if (bx < 1024) {
        // global max over tm, float4 coalesced: 8 float4 per thread
        const float4* tm4 = (const float4*)tm;
        size_t base = (size_t)bx * 256 + t;
        float m = -1e30f;
        #pragma unroll
        for (int k = 0; k < 8; k++) {
            float4 v = tm4[base + (size_t)k * 262144];
            m = fmaxf(m, fmaxf(fmaxf(v.x, v.y), fmaxf(v.z, v.w)));
        }
        smf[t] = m; __syncthreads();
        for (int s = 128; s > 0; s >>= 1) { if (t < s) smf[t] = fmaxf(smf[t], smf[t + s]); __syncthreads(); }
        if (t == 0) part[bx] = smf[0];
    } else if (bx < 1280) {
        // node0: 4 emb rows per block; sW staged through LDS (64x129 pad -> 2-way reads, free)
        int r0 = (bx - 1024) * 4;
        float* er = smf;           // [4][128]
        float* swt = smf + 512;    // [64][129]
        *(float2*)&er[t * 2] = *(const float2*)&emb[r0 * TD + t * 2];
        int k = t & 63, r = t >> 6;
        for (int kt = 0; kt < 8; kt++) {
            __syncthreads();   // er ready (it 0) / previous compute done
            const float4* src = (const float4*)(sW + kt * 64 * TD);
            #pragma unroll
            for (int rep = 0; rep < 8; rep++) {
                int f = rep * 256 + t;            // flat float4 idx in 64x128 tile
                float4 v = src[f];
                int row = f >> 5, col = (f & 31) * 4;
                float* d = swt + row * 129 + col;
                d[0] = v.x; d[1] = v.y; d[2] = v.z; d[3] = v.w;
            }
            __syncthreads();
            float acc = 0.f;
            const float* e = er + r * 128;
            const float* sw = swt + k * 129;
            #pragma unroll 4
            for (int i = 0; i < 128; i++) acc = fmaf(e[i], sw[i], acc);
            node0b[(size_t)(r0 + r) * HID + kt * 64 + k] = f2bf(acc + sb[kt * 64 + k]);
        }
    } else {
        // Wt[lh][o][k] = bf16(gW[lh][k][o]) via LDS tile transpose
        int g = bx - 1280; int lh = g >> 3, kt = g & 7;
        float* tile = smf;   // [64][65]
        const float4* src = (const float4*)(gW + ((size_t)lh * HID + kt * 64) * HD);
        #pragma unroll
        for (int rep = 0; rep < 4; rep++) {
            int f = rep * 256 + t;                // flat float4 idx in 64x64 tile
            float4 v = src[f];
            int row = f >> 4, col = (f & 15) * 4;
            float* d = tile + row * 65 + col;
            d[0] = v.x; d[1] = v.y; d[2] = v.z; d[3] = v.w;
        }
        __syncthreads();
        int o = t >> 2, ks = (t & 3) * 16;
        us pk[16];
        #pragma unroll
        for (int j = 0; j < 16; j++) pk[j] = f2bf(tile[(ks + j) * 65 + o]);
        us* dst = Wt + (size_t)lh * HD * HID + (size_t)o * HID + kt * 64 + ks;
        *(uint4*)dst = *(uint4*)pk;
        *(uint4*)(dst + 8) = *(uint4*)&pk[8];
    }
}

// ============ shared GEMM body: 64x64 tile, BK=64, double-buffered, 1 barrier/iter ======
__device__ __forceinline__ void gemm_body(const us* __restrict__ A, const us* __restrict__ W,
                                          const float* __restrict__ gav,
                                          us* __restrict__ outT, us* __restrict__ outR,
                                          float* __restrict__ esO, float* __restrict__ edO,
                                          int iblk, int b, int h, int t, us* sm) {
    us* As = sm;              // [2][64*72]
    us* Bs = sm + 2 * 4608;   // [2][64*72]
    int row = t >> 2, ks = t & 3;
    int l = t & 63, w = t >> 6, m = l & 15, q = l >> 4;
    size_t arow0 = (size_t)(b * NT + iblk * 64);
    const us* ar = A + (arow0 + row) * HID + ks * 16;
    const us* br = W + ((size_t)(h * HD + row)) * HID + ks * 16;
    f32x4 acc[4];
    #pragma unroll
    for (int ot = 0; ot < 4; ot++) acc[ot] = (f32x4){0.f, 0.f, 0.f, 0.f};
    {
        uint4 a0 = *(const uint4*)ar, a1 = *(const uint4*)(ar + 8);
        uint4 b0 = *(const uint4*)br, b1 = *(const uint4*)(br + 8);
        *(uint4*)&As[row * 72 + ks * 16] = a0; *(uint4*)&As[row * 72 + ks * 16 + 8] = a1;
        *(uint4*)&Bs[row * 72 + ks * 16] = b0; *(uint4*)&Bs[row * 72 + ks * 16 + 8] = b1;
    }
    for (int it = 0; it < 8; it++) {
        int cur = it & 1, nxt = cur ^ 1;
        uint4 a0, a1, b0, b1;
        if (it < 7) {
            int k0 = (it + 1) * 64;
            a0 = *(const uint4*)(ar + k0); a1 = *(const uint4*)(ar + k0 + 8);
            b0 = *(const uint4*)(br + k0); b1 = *(const uint4*)(br + k0 + 8);
        }
        __syncthreads();
        if (it < 7) {
            *(uint4*)&As[nxt * 4608 + row * 72 + ks * 16] = a0;
            *(uint4*)&As[nxt * 4608 + row * 72 + ks * 16 + 8] = a1;
            *(uint4*)&Bs[nxt * 4608 + row * 72 + ks * 16] = b0;
            *(uint4*)&Bs[nxt * 4608 + row * 72 + ks * 16 + 8] = b1;
        }
        const us* Ac = As + cur * 4608; const us* Bc = Bs + cur * 4608;
        #pragma unroll
        for (int kt = 0; kt < 2; kt++) {
            bf16x8 av = *(const bf16x8*)&Ac[(w * 16 + m) * 72 + kt * 32 + q * 8];
            #pragma unroll
            for (int ot = 0; ot < 4; ot++) {
                bf16x8 bv = *(const bf16x8*)&Bc[(ot * 16 + m) * 72 + kt * 32 + q * 8];
                acc[ot] = __builtin_amdgcn_mfma_f32_16x16x32_bf16(av, bv, acc[ot], 0, 0, 0);
            }
        }
    }
    const float* gas = gav + h * 2 * HD;
    float gs[4], gd[4];
    #pragma unroll
    for (int ot = 0; ot < 4; ot++) { gs[ot] = gas[ot * 16 + m]; gd[ot] = gas[HD + ot * 16 + m]; }
    size_t ebase = ((size_t)b * NH + h) * NT + iblk * 64;
    #pragma unroll
    for (int rr = 0; rr < 4; rr++) {
        float s = 0.f, d = 0.f;
        #pragma unroll
        for (int ot = 0; ot < 4; ot++) { float v = acc[ot][rr]; s = fmaf(v, gs[ot], s); d = fmaf(v, gd[ot], d); }
        #pragma unroll
        for (int mask = 1; mask < 16; mask <<= 1) { s += __shfl_xor(s, mask); d += __shfl_xor(d, mask); }
        if (m == 0) {
            int rowi = w * 16 + q * 4 + rr;
            esO[ebase + rowi] = s;
            edO[ebase + rowi] = d;
        }
    }
    #pragma unroll
    for (int ot = 0; ot < 4; ot++) {
        int col = h * HD + ot * 16 + m;
        #pragma unroll
        for (int rr = 0; rr < 4; rr++) {
            int i_loc = w * 16 + q * 4 + rr;
            float v = acc[ot][rr];
            if (outT) outT[(size_t)col * NT + iblk * 64 + i_loc] = f2bf(v);
            if (outR) outR[(arow0 + i_loc) * HID + col] = f2bf(v);
        }
    }
}

// ============ kphase1: ktw (blocks 0-2047) | layer-1 GEMM (2048-2175) ====================
__global__ __launch_bounds__(256) void kphase1(const float* __restrict__ tm, const int* __restrict__ adj,
                                               const float* __restrict__ part, us* __restrict__ TWb,
                                               const us* __restrict__ node0b, const us* __restrict__ Wt,
                                               const float* __restrict__ ga, us* __restrict__ Ht1,
                                               float* __restrict__ es1, float* __restrict__ ed1) {
    __shared__ __align__(16) us sm[4 * 4608];
    int bx = blockIdx.x, t = threadIdx.x;
    if (bx < 2048) {
        float* red = (float*)sm;
        float m = fmaxf(fmaxf(part[t * 4], part[t * 4 + 1]), fmaxf(part[t * 4 + 2], part[t * 4 + 3]));
        red[t] = m; __syncthreads();
        for (int s = 128; s > 0; s >>= 1) { if (t < s) red[t] = fmaxf(red[t], red[t + s]); __syncthreads(); }
        float tmx = red[0];
        #pragma unroll
        for (int it = 0; it < 4; it++) {
            size_t idx = (((size_t)bx * 4 + it) * 256 + t) * 4;
            float4 tv = *(const float4*)(tm + idx);
            int4 av = *(const int4*)(adj + idx);
            unsigned int r0 = av.x ? f2bf(__expf(0.1f * (tv.x - tmx))) : 0u;
            unsigned int r1 = av.y ? f2bf(__expf(0.1f * (tv.y - tmx))) : 0u;
            unsigned int r2 = av.z ? f2bf(__expf(0.1f * (tv.z - tmx))) : 0u;
            unsigned int r3 = av.w ? f2bf(__expf(0.1f * (tv.w - tmx))) : 0u;
            uint2 pk; pk.x = r0 | (r1 << 16); pk.y = r2 | (r3 << 16);
            *(uint2*)&TWb[idx] = pk;
        }
    } else {
        int g = bx - 2048;
        gemm_body(node0b, Wt, ga, Ht1, nullptr, es1, ed1, g & 15, 0, g >> 4, t, sm);
    }
}

// ============ layer-2 GEMM =============================================================
__global__ __launch_bounds__(256) void kgemm2(const us* __restrict__ node1b, const us* __restrict__ Wt2,
                                              const float* __restrict__ ga2, us* __restrict__ H2b,
                                              float* __restrict__ es2, float* __restrict__ ed2) {
    __shared__ __align__(16) us sm[4 * 4608];
    int x = blockIdx.x;
    gemm_body(node1b, Wt2, ga2, nullptr, H2b, es2, ed2, x & 15, x >> 4, blockIdx.y, threadIdx.x, sm);
}

// ============ layer-1 fused attention: BK=64, double-buffered, perm-packed P ============
__device__ __forceinline__ void p_tile(const us* __restrict__ twp, const float* __restrict__ edp,
                                       const us* __restrict__ htp, float es_i, float& lp,
                                       uint4& P0, uint4& P1, uint4& H0, uint4& H1) {
    union { uint4 v; us u[8]; } tw0, tw1;
    tw0.v = *(const uint4*)twp;
    tw1.v = *(const uint4*)(twp + 8);
    H0 = *(const uint4*)htp;
    H1 = *(const uint4*)(htp + 8);
    float ev[16];
    *(float4*)&ev[0]  = *(const float4*)edp;
    *(float4*)&ev[4]  = *(const float4*)(edp + 4);
    *(float4*)&ev[8]  = *(const float4*)(edp + 8);
    *(float4*)&ev[12] = *(const float4*)(edp + 12);
    unsigned int pk[8];
    #pragma unroll
    for (int r = 0; r < 4; r++) {
        float twa = bf2f(tw0.u[2 * r]), twb = bf2f(tw0.u[2 * r + 1]);
        float ea = es_i + ev[2 * r];     ea = fmaxf(ea, 0.2f * ea) * twa;
        float pa = tw0.u[2 * r] ? __expf(ea) : 0.f;
        float eb = es_i + ev[2 * r + 1]; eb = fmaxf(eb, 0.2f * eb) * twb;
        float pb = tw0.u[2 * r + 1] ? __expf(eb) : 0.f;
        lp += __uint_as_float(__float_as_uint(pa) & 0xFFFF0000u)
            + __uint_as_float(__float_as_uint(pb) & 0xFFFF0000u);
        pk[r] = __builtin_amdgcn_perm(__float_as_uint(pb), __float_as_uint(pa), 0x07060302);
    }
    #pragma unroll
    for (int r = 0; r < 4; r++) {
        float twa = bf2f(tw1.u[2 * r]), twb = bf2f(tw1.u[2 * r + 1]);
        float ea = es_i + ev[8 + 2 * r];     ea = fmaxf(ea, 0.2f * ea) * twa;
        float pa = tw1.u[2 * r] ? __expf(ea) : 0.f;
        float eb = es_i + ev[8 + 2 * r + 1]; eb = fmaxf(eb, 0.2f * eb) * twb;
        float pb = tw1.u[2 * r + 1] ? __expf(eb) : 0.f;
        lp += __uint_as_float(__float_as_uint(pa) & 0xFFFF0000u)
            + __uint_as_float(__float_as_uint(pb) & 0xFFFF0000u);
        pk[4 + r] = __builtin_amdgcn_perm(__float_as_uint(pb), __float_as_uint(pa), 0x07060302);
    }
    P0 = make_uint4(pk[0], pk[1], pk[2], pk[3]);
    P1 = make_uint4(pk[4], pk[5], pk[6], pk[7]);
}

__global__ __launch_bounds__(256) void kattn1(const us* __restrict__ TWb, const us* __restrict__ Ht,
                                              const float* __restrict__ es, const float* __restrict__ ed,
                                              us* __restrict__ node1b) {
    int x = blockIdx.x; int iblk = x & 15; int b = x >> 4; int h = blockIdx.y;
    int t = threadIdx.x;
    __shared__ __align__(16) us Ps[2 * 4608];
    __shared__ __align__(16) us Hs[2 * 4608];
    __shared__ float Ls[64 * 5];
    __shared__ float invl_s[64];
    int i = t >> 2, js = t & 3;
    int l = t & 63, w = t >> 6, m = l & 15, q = l >> 4;
    float es_i = es[h * NT + iblk * 64 + i];
    const us* twrow = TWb + ((size_t)(b * NT) + iblk * 64 + i) * NT + js * 16;
    const float* edh = ed + h * NT + js * 16;
    const us* htrow = Ht + ((size_t)(h * HD) + i) * NT + js * 16;
    f32x4 acc[4];
    #pragma unroll
    for (int ot = 0; ot < 4; ot++) acc[ot] = (f32x4){0.f, 0.f, 0.f, 0.f};
    float lp = 0.f;
    uint4 P0, P1, H0, H1;
    p_tile(twrow, edh, htrow, es_i, lp, P0, P1, H0, H1);
    {
        us* Pd = Ps + i * 72 + js * 16;
        us* Hd = Hs + i * 72 + js * 16;
        *(uint4*)Pd = P0; *(uint4*)(Pd + 8) = P1;
        *(uint4*)Hd = H0; *(uint4*)(Hd + 8) = H1;
    }
    for (int it = 0; it < 16; it++) {
        int cur = it & 1;
        if (it < 15) {
            int j0 = (it + 1) * 64;
            p_tile(twrow + j0, edh + j0, htrow + j0, es_i, lp, P0, P1, H0, H1);
        }
        __syncthreads();
        if (it < 15) {
            int nxt = cur ^ 1;
            us* Pd = Ps + nxt * 4608 + i * 72 + js * 16;
            us* Hd = Hs + nxt * 4608 + i * 72 + js * 16;
            *(uint4*)Pd = P0; *(uint4*)(Pd + 8) = P1;
            *(uint4*)Hd = H0; *(uint4*)(Hd + 8) = H1;
        }
        const us* Pc = Ps + cur * 4608; const us* Hc = Hs + cur * 4608;
        #pragma unroll
        for (int kt = 0; kt < 2; kt++) {
            bf16x8 av = *(const bf16x8*)&Pc[(w * 16 + m) * 72 + kt * 32 + q * 8];
            #pragma unroll
            for (int ot = 0; ot < 4; ot++) {
                bf16x8 bv = *(const bf16x8*)&Hc[(ot * 16 + m) * 72 + kt * 32 + q * 8];
                acc[ot] = __builtin_amdgcn_mfma_f32_16x16x32_bf16(av, bv, acc[ot], 0, 0, 0);
            }
        }
    }
    Ls[i * 5 + js] = lp;
    __syncthreads();
    if (t < 64) {
        float s = Ls[t * 5] + Ls[t * 5 + 1] + Ls[t * 5 + 2] + Ls[t * 5 + 3];
        invl_s[t] = 1.f / s;
    }
    __syncthreads();
    #pragma unroll
    for (int ot = 0; ot < 4; ot++) {
        int col = h * HD + ot * 16 + m;
        #pragma unroll
        for (int rr = 0; rr < 4; rr++) {
            int i_loc = w * 16 + q * 4 + rr;
            float v = acc[ot][rr] * invl_s[i_loc];
            v = v > 0.f ? v : (__expf(v) - 1.f);  // ELU
            node1b[(size_t)(b * NT + iblk * 64 + i_loc) * HID + col] = f2bf(v);
        }
    }
}

// ============ layer-2 attention phase A: partial PV over 64-j slices (1024 blocks) ======
__global__ __launch_bounds__(256) void kattn2a(const us* __restrict__ TWb, const us* __restrict__ H2b,
                                               const float* __restrict__ es2, const float* __restrict__ ed2,
                                               const int* __restrict__ topic_ids,
                                               float* __restrict__ ppv, float* __restrict__ pl) {
    int js = blockIdx.x, h = blockIdx.y, b = blockIdx.z;
    int t = threadIdx.x;
    __shared__ float pls[64];
    __shared__ float red[256];
    int qi = topic_ids[b];
    if (t < 64) {
        int j = js * 64 + t;
        float esq = es2[((size_t)b * NH + h) * NT + qi];
        us twu = TWb[((size_t)(b * NT) + qi) * NT + j];
        float tw = bf2f(twu);
        float e = esq + ed2[((size_t)b * NH + h) * NT + j];
        e = fmaxf(e, 0.2f * e) * tw;
        float p = twu ? __expf(e) : 0.f;
        pls[t] = p;
        float lsum = p;
        #pragma unroll
        for (int mask = 1; mask < 64; mask <<= 1) lsum += __shfl_xor(lsum, mask);
        if (t == 0) pl[((size_t)b * NH + h) * 16 + js] = lsum;
    }
    __syncthreads();
    int o = t & 63, jg = t >> 6;
    float acc = 0.f;
    const us* hb = H2b + ((size_t)(b * NT) + js * 64 + jg * 16) * HID + h * HD + o;
    #pragma unroll
    for (int jj = 0; jj < 16; jj++)
        acc = fmaf(pls[jg * 16 + jj], bf2f(hb[(size_t)jj * HID]), acc);
    red[t] = acc; __syncthreads();
    if (t < 64) {
        float pv = red[t] + red[t + 64] + red[t + 128] + red[t + 192];
        ppv[(((size_t)b * NH + h) * 16 + js) * HD + t] = pv;
    }
}

// ============ final head: reduce partials -> ELU -> combined -> fc1 relu -> fc2 =========
__global__ __launch_bounds__(256) void khead(const float* __restrict__ ppv, const float* __restrict__ pl,
                                             const float* __restrict__ attr,
                                             const float* __restrict__ aW, const float* __restrict__ ab,
                                             const float* __restrict__ fc1W, const float* __restrict__ fc1b,
                                             const float* __restrict__ fc2W, const float* __restrict__ fc2b,
                                             float* __restrict__ out) {
    int b = blockIdx.x, t = threadIdx.x;
    __shared__ float comb[HID];
    __shared__ float red[256];
    __shared__ float linv[NH];
    if (t < NH) {
        float lsum = 0.f;
        #pragma unroll
        for (int js = 0; js < 16; js++) lsum += pl[((size_t)b * NH + t) * 16 + js];
        linv[t] = 1.f / lsum;
    }
    __syncthreads();
    float av = attr[b];
    for (int k = t; k < HID; k += 256) {
        int h = k >> 6, o = k & 63;
        float pv = 0.f;
        #pragma unroll
        for (int js = 0; js < 16; js++) pv += ppv[(((size_t)b * NH + h) * 16 + js) * HD + o];
        float v = pv * linv[h];
        v = v > 0.f ? v : (__expf(v) - 1.f);  // ELU
        comb[k] = v + av * aW[k] + ab[k];
    }
    __syncthreads();
    float part = 0.f;
    for (int k = t; k < HID; k += 256) {
        const float4* wr = (const float4*)(fc1W + (size_t)k * HID);
        float acc = 0.f;
        #pragma unroll 4
        for (int mm = 0; mm < HID / 4; mm++) {
            float4 w4 = wr[mm];
            float4 c4 = *(const float4*)(comb + mm * 4);
            acc += w4.x * c4.x + w4.y * c4.y + w4.z * c4.z + w4.w * c4.w;
        }
        float hk = fmaxf(acc + fc1b[k], 0.f);
        part = fmaf(hk, fc2W[k], part);
    }
    red[t] = part; __syncthreads();
    for (int s = 128; s > 0; s >>= 1) { if (t < s) red[t] += red[t + s]; __syncthreads(); }
    if (t == 0) out[b] = red[0] + fc2b[0];
}

extern "C" void kernel_launch(void* const* d_in, const int* in_sizes, int n_in,
                              void* d_out, int out_size, void* d_ws, size_t ws_size,
                              hipStream_t stream) {
    const int*   topic_ids = (const int*)d_in[0];
    const int*   adj       = (const int*)d_in[1];
    const float* tm        = (const float*)d_in[2];
    const float* attr      = (const float*)d_in[3];
    const float* emb       = (const float*)d_in[4];
    const float* sW        = (const float*)d_in[5];
    const float* sb        = (const float*)d_in[6];
    const float* aW        = (const float*)d_in[7];
    const float* ab        = (const float*)d_in[8];
    const float* gW        = (const float*)d_in[9];   // (2,8,512,64)
    const float* ga        = (const float*)d_in[10];  // (2,8,128,1)
    const float* fc1W      = (const float*)d_in[11];
    const float* fc1b      = (const float*)d_in[12];
    const float* fc2W      = (const float*)d_in[13];
    const float* fc2b      = (const float*)d_in[14];
    float* out = (float*)d_out;

    char* p = (char*)d_ws;
    us* TWb    = (us*)p; p += sizeof(us) * (size_t)NB * NT * NT;        // 16.8 MB
    us* node0b = (us*)p; p += sizeof(us) * (size_t)NT * HID;            // 1 MB
    us* Wt     = (us*)p; p += sizeof(us) * (size_t)2 * NH * HD * HID;   // 1 MB
    us* Ht1    = (us*)p; p += sizeof(us) * (size_t)HID * NT;            // 1 MB
    us* node1b = (us*)p; p += sizeof(us) * (size_t)NB * NT * HID;       // 8 MB
    us* H2b    = (us*)p; p += sizeof(us) * (size_t)NB * NT * HID;       // 8 MB
    float* es1  = (float*)p; p += sizeof(float) * NH * NT;
    float* ed1  = (float*)p; p += sizeof(float) * NH * NT;
    float* es2  = (float*)p; p += sizeof(float) * NB * NH * NT;
    float* ed2  = (float*)p; p += sizeof(float) * NB * NH * NT;
    float* ppv  = (float*)p; p += sizeof(float) * NB * NH * 16 * HD;
    float* pl   = (float*)p; p += sizeof(float) * NB * NH * 16;
    float* part = (float*)p; p += sizeof(float) * 1024;

    kprep<<<1408, 256, 0, stream>>>(tm, part, emb, sW, sb, node0b, gW, Wt);
    kphase1<<<2176, 256, 0, stream>>>(tm, adj, part, TWb, node0b, Wt, ga, Ht1, es1, ed1);
    kattn1<<<dim3(16 * NB, NH), 256, 0, stream>>>(TWb, Ht1, es1, ed1, node1b);
    kgemm2<<<dim3(16 * NB, NH), 256, 0, stream>>>(node1b, Wt + (size_t)NH * HD * HID,
                                                  ga + NH * 2 * HD, H2b, es2, ed2);
    kattn2a<<<dim3(16, NH, NB), 256, 0, stream>>>(TWb, H2b, es2, ed2, topic_ids, ppv, pl);
    khead<<<NB, 256, 0, stream>>>(ppv, pl, attr, aW, ab, fc1W, fc1b, fc2W, fc2b, out);
}

// Round 8
// 239.701 us; speedup vs baseline: 1.1337x; 1.1337x over previous
//
#include <hip/hip_runtime.h>

#define NT 1024      // N_TOPICS
#define TD 128       // TOPIC_DIM
#define HID 512      // HIDDEN
#define NH 8         // N_HEADS
#define HD 64        // HEAD_DIM
#define NB 8         // BATCH

typedef unsigned short us;
typedef short bf16x8 __attribute__((ext_vector_type(8)));
typedef float f32x4 __attribute__((ext_vector_type(4)));

#define LOG2E 1.44269504f

__device__ __forceinline__ us f2bf(float x) {
    unsigned int u = __float_as_uint(x);
    return (us)((u + 0x7FFFu + ((u >> 16) & 1u)) >> 16);
}
__device__ __forceinline__ float bf2f(us s) {
    return __uint_as_float(((unsigned int)s) << 16);
}

// ============ kprep: kmax (0-1023) | node0 MFMA GEMM (1024-1151) | gW transpose (1152-1279)
__global__ __launch_bounds__(256) void kprep(const float* __restrict__ tm, float* __restrict__ part,
                                             const float* __restrict__ emb, const float* __restrict__ sW,
                                             const float* __restrict__ sb, us* __restrict__ node0b,
                                             const float* __restrict__ gW, us* __restrict__ Wt) {
    __shared__ __align__(16) float smf[8768];   // 35 KB shared by branches
    int bx = blockIdx.x, t = threadIdx.x;
    if (bx < 1024) {
        // global max over tm, float4 coalesced
        const float4* tm4 = (const float4*)tm;
        size_t base = (size_t)bx * 256 + t;
        float m = -1e30f;
        #pragma unroll
        for (int k = 0; k < 8; k++) {
            float4 v = tm4[base + (size_t)k * 262144];
            m = fmaxf(m, fmaxf(fmaxf(v.x, v.y), fmaxf(v.z, v.w)));
        }
        smf[t] = m; __syncthreads();
        for (int s = 128; s > 0; s >>= 1) { if (t < s) smf[t] = fmaxf(smf[t], smf[t + s]); __syncthreads(); }
        if (t == 0) part[bx] = smf[0];
    } else if (bx < 1152) {
        // node0 = emb @ sW^T + sb via MFMA. block: (iblk 16) x (oseg 8); K=128, one barrier.
        int g = bx - 1024; int iblk = g & 15, oseg = g >> 4;
        us* As = (us*)smf;              // [64][136]
        us* Bs = (us*)smf + 64 * 136;   // [64][136]
        const float4* esrc = (const float4*)(emb + (size_t)iblk * 64 * TD);
        const float4* wsrc = (const float4*)(sW + (size_t)oseg * 64 * TD);
        #pragma unroll
        for (int rep = 0; rep < 8; rep++) {
            int f = rep * 256 + t;           // 2048 float4 = 64 rows x 32 f4
            int row = f >> 5, c4 = f & 31;
            float4 av = esrc[f];
            float4 bv = wsrc[f];
            us pa[4] = {f2bf(av.x), f2bf(av.y), f2bf(av.z), f2bf(av.w)};
            us pb[4] = {f2bf(bv.x), f2bf(bv.y), f2bf(bv.z), f2bf(bv.w)};
            *(uint2*)&As[row * 136 + c4 * 4] = *(uint2*)pa;
            *(uint2*)&Bs[row * 136 + c4 * 4] = *(uint2*)pb;
        }
        __syncthreads();
        int l = t & 63, w = t >> 6, m = l & 15, q = l >> 4;
        f32x4 acc[4];
        #pragma unroll
        for (int ot = 0; ot < 4; ot++) acc[ot] = (f32x4){0.f, 0.f, 0.f, 0.f};
        #pragma unroll
        for (int ks = 0; ks < 4; ks++) {
            bf16x8 a = *(const bf16x8*)&As[(w * 16 + m) * 136 + ks * 32 + q * 8];
            #pragma unroll
            for (int ot = 0; ot < 4; ot++) {
                bf16x8 b = *(const bf16x8*)&Bs[(ot * 16 + m) * 136 + ks * 32 + q * 8];
                acc[ot] = __builtin_amdgcn_mfma_f32_16x16x32_bf16(a, b, acc[ot], 0, 0, 0);
            }
        }
        #pragma unroll
        for (int ot = 0; ot < 4; ot++) {
            int col = oseg * 64 + ot * 16 + m;
            float sbv = sb[col];
            #pragma unroll
            for (int rr = 0; rr < 4; rr++) {
                int rowi = iblk * 64 + w * 16 + q * 4 + rr;
                node0b[(size_t)rowi * HID + col] = f2bf(acc[ot][rr] + sbv);
            }
        }
    } else {
        // Wt[lh][o][k] = bf16(gW[lh][k][o]) via LDS tile transpose
        int g = bx - 1152; int lh = g >> 3, kt = g & 7;
        float* tile = smf;   // [64][65]
        const float4* src = (const float4*)(gW + ((size_t)lh * HID + kt * 64) * HD);
        #pragma unroll
        for (int rep = 0; rep < 4; rep++) {
            int f = rep * 256 + t;
            float4 v = src[f];
            int row = f >> 4, col = (f & 15) * 4;
            float* d = tile + row * 65 + col;
            d[0] = v.x; d[1] = v.y; d[2] = v.z; d[3] = v.w;
        }
        __syncthreads();
        int o = t >> 2, ks = (t & 3) * 16;
        us pk[16];
        #pragma unroll
        for (int j = 0; j < 16; j++) pk[j] = f2bf(tile[(ks + j) * 65 + o]);
        us* dst = Wt + (size_t)lh * HD * HID + (size_t)o * HID + kt * 64 + ks;
        *(uint4*)dst = *(uint4*)pk;
        *(uint4*)(dst + 8) = *(uint4*)&pk[8];
    }
}

// ============ shared GEMM body: 64x64 tile, BK=64, dbuf, distance-2 global pipeline =====
__device__ __forceinline__ void gemm_body(const us* __restrict__ A, const us* __restrict__ W,
                                          const float* __restrict__ gav,
                                          us* __restrict__ outT, us* __restrict__ outR,
                                          float* __restrict__ esO, float* __restrict__ edO,
                                          int iblk, int b, int h, int t, us* sm) {
    us* As = sm;              // [2][64*72]
    us* Bs = sm + 2 * 4608;   // [2][64*72]
    int row = t >> 2, ks = t & 3;
    int l = t & 63, w = t >> 6, m = l & 15, q = l >> 4;
    size_t arow0 = (size_t)(b * NT + iblk * 64);
    const us* ar = A + (arow0 + row) * HID + ks * 16;
    const us* br = W + ((size_t)(h * HD + row)) * HID + ks * 16;
    f32x4 acc[4];
    #pragma unroll
    for (int ot = 0; ot < 4; ot++) acc[ot] = (f32x4){0.f, 0.f, 0.f, 0.f};
    {   // tile 0 direct to buf 0
        uint4 x0 = *(const uint4*)ar, x1 = *(const uint4*)(ar + 8);
        uint4 y0 = *(const uint4*)br, y1 = *(const uint4*)(br + 8);
        *(uint4*)&As[row * 72 + ks * 16] = x0; *(uint4*)&As[row * 72 + ks * 16 + 8] = x1;
        *(uint4*)&Bs[row * 72 + ks * 16] = y0; *(uint4*)&Bs[row * 72 + ks * 16 + 8] = y1;
    }
    uint4 a0 = *(const uint4*)(ar + 64), a1 = *(const uint4*)(ar + 72);
    uint4 b0 = *(const uint4*)(br + 64), b1 = *(const uint4*)(br + 72);
    for (int it = 0; it < 8; it++) {
        int cur = it & 1, nxt = cur ^ 1;
        uint4 na0, na1, nb0, nb1;
        if (it < 6) {
            int k0 = (it + 2) * 64;
            na0 = *(const uint4*)(ar + k0); na1 = *(const uint4*)(ar + k0 + 8);
            nb0 = *(const uint4*)(br + k0); nb1 = *(const uint4*)(br + k0 + 8);
        }
        __syncthreads();
        if (it < 7) {
            *(uint4*)&As[nxt * 4608 + row * 72 + ks * 16] = a0;
            *(uint4*)&As[nxt * 4608 + row * 72 + ks * 16 + 8] = a1;
            *(uint4*)&Bs[nxt * 4608 + row * 72 + ks * 16] = b0;
            *(uint4*)&Bs[nxt * 4608 + row * 72 + ks * 16 + 8] = b1;
        }
        const us* Ac = As + cur * 4608; const us* Bc = Bs + cur * 4608;
        #pragma unroll
        for (int kt = 0; kt < 2; kt++) {
            bf16x8 av = *(const bf16x8*)&Ac[(w * 16 + m) * 72 + kt * 32 + q * 8];
            #pragma unroll
            for (int ot = 0; ot < 4; ot++) {
                bf16x8 bv = *(const bf16x8*)&Bc[(ot * 16 + m) * 72 + kt * 32 + q * 8];
                acc[ot] = __builtin_amdgcn_mfma_f32_16x16x32_bf16(av, bv, acc[ot], 0, 0, 0);
            }
        }
        if (it < 6) { a0 = na0; a1 = na1; b0 = nb0; b1 = nb1; }
    }
    const float* gas = gav + h * 2 * HD;
    float gs[4], gd[4];
    #pragma unroll
    for (int ot = 0; ot < 4; ot++) { gs[ot] = gas[ot * 16 + m]; gd[ot] = gas[HD + ot * 16 + m]; }
    size_t ebase = ((size_t)b * NH + h) * NT + iblk * 64;
    #pragma unroll
    for (int rr = 0; rr < 4; rr++) {
        float s = 0.f, d = 0.f;
        #pragma unroll
        for (int ot = 0; ot < 4; ot++) { float v = acc[ot][rr]; s = fmaf(v, gs[ot], s); d = fmaf(v, gd[ot], d); }
        #pragma unroll
        for (int mask = 1; mask < 16; mask <<= 1) { s += __shfl_xor(s, mask); d += __shfl_xor(d, mask); }
        if (m == 0) {
            int rowi = w * 16 + q * 4 + rr;
            esO[ebase + rowi] = s;
            edO[ebase + rowi] = d;
        }
    }
    #pragma unroll
    for (int ot = 0; ot < 4; ot++) {
        int col = h * HD + ot * 16 + m;
        #pragma unroll
        for (int rr = 0; rr < 4; rr++) {
            int i_loc = w * 16 + q * 4 + rr;
            float v = acc[ot][rr];
            if (outT) outT[(size_t)col * NT + iblk * 64 + i_loc] = f2bf(v);
            if (outR) outR[(arow0 + i_loc) * HID + col] = f2bf(v);
        }
    }
}

// ============ kphase1: ktw (0-2047, stores tw*log2e) | layer-1 GEMM (2048-2175) =========
__global__ __launch_bounds__(256) void kphase1(const float* __restrict__ tm, const int* __restrict__ adj,
                                               const float* __restrict__ part, us* __restrict__ TWb,
                                               const us* __restrict__ node0b, const us* __restrict__ Wt,
                                               const float* __restrict__ ga, us* __restrict__ Ht1,
                                               float* __restrict__ es1, float* __restrict__ ed1) {
    __shared__ __align__(16) us sm[4 * 4608];
    int bx = blockIdx.x, t = threadIdx.x;
    if (bx < 2048) {
        float* red = (float*)sm;
        float m = fmaxf(fmaxf(part[t * 4], part[t * 4 + 1]), fmaxf(part[t * 4 + 2], part[t * 4 + 3]));
        red[t] = m; __syncthreads();
        for (int s = 128; s > 0; s >>= 1) { if (t < s) red[t] = fmaxf(red[t], red[t + s]); __syncthreads(); }
        float tmx = red[0];
        #pragma unroll
        for (int it = 0; it < 4; it++) {
            size_t idx = (((size_t)bx * 4 + it) * 256 + t) * 4;
            float4 tv = *(const float4*)(tm + idx);
            int4 av = *(const int4*)(adj + idx);
            unsigned int r0 = av.x ? f2bf(__expf(0.1f * (tv.x - tmx)) * LOG2E) : 0u;
            unsigned int r1 = av.y ? f2bf(__expf(0.1f * (tv.y - tmx)) * LOG2E) : 0u;
            unsigned int r2 = av.z ? f2bf(__expf(0.1f * (tv.z - tmx)) * LOG2E) : 0u;
            unsigned int r3 = av.w ? f2bf(__expf(0.1f * (tv.w - tmx)) * LOG2E) : 0u;
            uint2 pk; pk.x = r0 | (r1 << 16); pk.y = r2 | (r3 << 16);
            *(uint2*)&TWb[idx] = pk;
        }
    } else {
        int g = bx - 2048;
        gemm_body(node0b, Wt, ga, Ht1, nullptr, es1, ed1, g & 15, 0, g >> 4, t, sm);
    }
}

// ============ layer-2 GEMM =============================================================
__global__ __launch_bounds__(256) void kgemm2(const us* __restrict__ node1b, const us* __restrict__ Wt2,
                                              const float* __restrict__ ga2, us* __restrict__ H2b,
                                              float* __restrict__ es2, float* __restrict__ ed2) {
    __shared__ __align__(16) us sm[4 * 4608];
    int x = blockIdx.x;
    gemm_body(node1b, Wt2, ga2, nullptr, H2b, es2, ed2, x & 15, x >> 4, blockIdx.y, threadIdx.x, sm);
}

// ============ layer-1 fused attention: distance-2 pipeline, ed in LDS, exp2 =============
__device__ __forceinline__ void compute_p(uint4 T0, uint4 T1, const us* __restrict__ eds, int jbase,
                                          float es_i, float& lp, uint4& P01, uint4& P23) {
    union U { uint4 v; us u[8]; };
    U a; a.v = T0; U c; c.v = T1;
    U e0, e1;
    e0.v = *(const uint4*)&eds[jbase];
    e1.v = *(const uint4*)&eds[jbase + 8];
    unsigned int pk[8];
    #pragma unroll
    for (int r = 0; r < 4; r++) {
        float twa = bf2f(a.u[2 * r]), twb = bf2f(a.u[2 * r + 1]);
        float ea = es_i + bf2f(e0.u[2 * r]);
        ea = fmaxf(ea, 0.2f * ea) * twa;
        float pa = a.u[2 * r] ? exp2f(ea) : 0.f;
        float eb = es_i + bf2f(e0.u[2 * r + 1]);
        eb = fmaxf(eb, 0.2f * eb) * twb;
        float pb = a.u[2 * r + 1] ? exp2f(eb) : 0.f;
        lp += __uint_as_float(__float_as_uint(pa) & 0xFFFF0000u)
            + __uint_as_float(__float_as_uint(pb) & 0xFFFF0000u);
        pk[r] = __builtin_amdgcn_perm(__float_as_uint(pb), __float_as_uint(pa), 0x07060302);
    }
    #pragma unroll
    for (int r = 0; r < 4; r++) {
        float twa = bf2f(c.u[2 * r]), twb = bf2f(c.u[2 * r + 1]);
        float ea = es_i + bf2f(e1.u[2 * r]);
        ea = fmaxf(ea, 0.2f * ea) * twa;
        float pa = c.u[2 * r] ? exp2f(ea) : 0.f;
        float eb = es_i + bf2f(e1.u[2 * r + 1]);
        eb = fmaxf(eb, 0.2f * eb) * twb;
        float pb = c.u[2 * r + 1] ? exp2f(eb) : 0.f;
        lp += __uint_as_float(__float_as_uint(pa) & 0xFFFF0000u)
            + __uint_as_float(__float_as_uint(pb) & 0xFFFF0000u);
        pk[4 + r] = __builtin_amdgcn_perm(__float_as_uint(pb), __float_as_uint(pa), 0x07060302);
    }
    P01 = make_uint4(pk[0], pk[1], pk[2], pk[3]);
    P23 = make_uint4(pk[4], pk[5], pk[6], pk[7]);
}

__global__ __launch_bounds__(256) void kattn1(const us* __restrict__ TWb, const us* __restrict__ Ht,
                                              const float* __restrict__ es, const float* __restrict__ ed,
                                              us* __restrict__ node1b) {
    int x = blockIdx.x; int iblk = x & 15; int b = x >> 4; int h = blockIdx.y;
    int t = threadIdx.x;
    __shared__ __align__(16) us Ps[2 * 4608];
    __shared__ __align__(16) us Hs[2 * 4608];
    __shared__ __align__(16) us eds[1024];      // bf16 e_dst row for this head
    __shared__ float Ls[64 * 5];
    __shared__ float invl_s[64];
    int i = t >> 2, js = t & 3;
    int l = t & 63, w = t >> 6, m = l & 15, q = l >> 4;
    {   // stage ed -> bf16 LDS
        float4 ev = *(const float4*)&ed[h * NT + t * 4];
        us pk[4] = {f2bf(ev.x), f2bf(ev.y), f2bf(ev.z), f2bf(ev.w)};
        *(uint2*)&eds[t * 4] = *(uint2*)pk;
    }
    float es_i = es[h * NT + iblk * 64 + i];
    const us* twrow = TWb + ((size_t)(b * NT) + iblk * 64 + i) * NT + js * 16;
    const us* htrow = Ht + ((size_t)(h * HD) + i) * NT + js * 16;
    f32x4 acc[4];
    #pragma unroll
    for (int ot = 0; ot < 4; ot++) acc[ot] = (f32x4){0.f, 0.f, 0.f, 0.f};
    float lp = 0.f;
    uint4 T0, T1, Hh0, Hh1;
    // tile 0: load, compute, write buf0
    T0 = *(const uint4*)twrow; T1 = *(const uint4*)(twrow + 8);
    Hh0 = *(const uint4*)htrow; Hh1 = *(const uint4*)(htrow + 8);
    __syncthreads();   // eds ready
    {
        uint4 p01, p23;
        compute_p(T0, T1, eds, js * 16, es_i, lp, p01, p23);
        us* Pd = Ps + i * 72 + js * 16;
        us* Hd = Hs + i * 72 + js * 16;
        *(uint4*)Pd = p01; *(uint4*)(Pd + 8) = p23;
        *(uint4*)Hd = Hh0; *(uint4*)(Hd + 8) = Hh1;
    }
    // tile 1 loads
    T0 = *(const uint4*)(twrow + 64); T1 = *(const uint4*)(twrow + 72);
    Hh0 = *(const uint4*)(htrow + 64); Hh1 = *(const uint4*)(htrow + 72);
    for (int it = 0; it < 16; it++) {
        int cur = it & 1, nxt = cur ^ 1;
        uint4 nT0, nT1, nH0, nH1;
        if (it < 14) {
            int j0 = (it + 2) * 64;
            nT0 = *(const uint4*)(twrow + j0); nT1 = *(const uint4*)(twrow + j0 + 8);
            nH0 = *(const uint4*)(htrow + j0); nH1 = *(const uint4*)(htrow + j0 + 8);
        }
        uint4 p01, p23;
        if (it < 15) compute_p(T0, T1, eds, (it + 1) * 64 + js * 16, es_i, lp, p01, p23);
        __syncthreads();
        if (it < 15) {
            us* Pd = Ps + nxt * 4608 + i * 72 + js * 16;
            us* Hd = Hs + nxt * 4608 + i * 72 + js * 16;
            *(uint4*)Pd = p01; *(uint4*)(Pd + 8) = p23;
            *(uint4*)Hd = Hh0; *(uint4*)(Hd + 8) = Hh1;
        }
        const us* Pc = Ps + cur * 4608; const us* Hc = Hs + cur * 4608;
        #pragma unroll
        for (int kt = 0; kt < 2; kt++) {
            bf16x8 av = *(const bf16x8*)&Pc[(w * 16 + m) * 72 + kt * 32 + q * 8];
            #pragma unroll
            for (int ot = 0; ot < 4; ot++) {
                bf16x8 bv = *(const bf16x8*)&Hc[(ot * 16 + m) * 72 + kt * 32 + q * 8];
                acc[ot] = __builtin_amdgcn_mfma_f32_16x16x32_bf16(av, bv, acc[ot], 0, 0, 0);
            }
        }
        if (it < 14) { T0 = nT0; T1 = nT1; Hh0 = nH0; Hh1 = nH1; }
    }
    Ls[i * 5 + js] = lp;
    __syncthreads();
    if (t < 64) {
        float s = Ls[t * 5] + Ls[t * 5 + 1] + Ls[t * 5 + 2] + Ls[t * 5 + 3];
        invl_s[t] = 1.f / s;
    }
    __syncthreads();
    #pragma unroll
    for (int ot = 0; ot < 4; ot++) {
        int col = h * HD + ot * 16 + m;
        #pragma unroll
        for (int rr = 0; rr < 4; rr++) {
            int i_loc = w * 16 + q * 4 + rr;
            float v = acc[ot][rr] * invl_s[i_loc];
            v = v > 0.f ? v : (__expf(v) - 1.f);  // ELU
            node1b[(size_t)(b * NT + iblk * 64 + i_loc) * HID + col] = f2bf(v);
        }
    }
}

// ============ layer-2 attention phase A: partial PV over 64-j slices (1024 blocks) ======
__global__ __launch_bounds__(256) void kattn2a(const us* __restrict__ TWb, const us* __restrict__ H2b,
                                               const float* __restrict__ es2, const float* __restrict__ ed2,
                                               const int* __restrict__ topic_ids,
                                               float* __restrict__ ppv, float* __restrict__ pl) {
    int js = blockIdx.x, h = blockIdx.y, b = blockIdx.z;
    int t = threadIdx.x;
    __shared__ float pls[64];
    __shared__ float red[256];
    int qi = topic_ids[b];
    if (t < 64) {
        int j = js * 64 + t;
        float esq = es2[((size_t)b * NH + h) * NT + qi];
        us twu = TWb[((size_t)(b * NT) + qi) * NT + j];
        float tw = bf2f(twu);    // tw * log2e
        float e = esq + ed2[((size_t)b * NH + h) * NT + j];
        e = fmaxf(e, 0.2f * e) * tw;
        float p = twu ? exp2f(e) : 0.f;
        pls[t] = p;
        float lsum = p;
        #pragma unroll
        for (int mask = 1; mask < 64; mask <<= 1) lsum += __shfl_xor(lsum, mask);
        if (t == 0) pl[((size_t)b * NH + h) * 16 + js] = lsum;
    }
    __syncthreads();
    int o = t & 63, jg = t >> 6;
    float acc = 0.f;
    const us* hb = H2b + ((size_t)(b * NT) + js * 64 + jg * 16) * HID + h * HD + o;
    #pragma unroll
    for (int jj = 0; jj < 16; jj++)
        acc = fmaf(pls[jg * 16 + jj], bf2f(hb[(size_t)jj * HID]), acc);
    red[t] = acc; __syncthreads();
    if (t < 64) {
        float pv = red[t] + red[t + 64] + red[t + 128] + red[t + 192];
        ppv[(((size_t)b * NH + h) * 16 + js) * HD + t] = pv;
    }
}

// ============ final head: reduce partials -> ELU -> combined -> fc1 relu -> fc2 =========
__global__ __launch_bounds__(256) void khead(const float* __restrict__ ppv, const float* __restrict__ pl,
                                             const float* __restrict__ attr,
                                             const float* __restrict__ aW, const float* __restrict__ ab,
                                             const float* __restrict__ fc1W, const float* __restrict__ fc1b,
                                             const float* __restrict__ fc2W, const float* __restrict__ fc2b,
                                             float* __restrict__ out) {
    int b = blockIdx.x, t = threadIdx.x;
    __shared__ float comb[HID];
    __shared__ float red[256];
    __shared__ float linv[NH];
    if (t < NH) {
        float lsum = 0.f;
        #pragma unroll
        for (int js = 0; js < 16; js++) lsum += pl[((size_t)b * NH + t) * 16 + js];
        linv[t] = 1.f / lsum;
    }
    __syncthreads();
    float av = attr[b];
    for (int k = t; k < HID; k += 256) {
        int h = k >> 6, o = k & 63;
        float pv = 0.f;
        #pragma unroll
        for (int js = 0; js < 16; js++) pv += ppv[(((size_t)b * NH + h) * 16 + js) * HD + o];
        float v = pv * linv[h];
        v = v > 0.f ? v : (__expf(v) - 1.f);  // ELU
        comb[k] = v + av * aW[k] + ab[k];
    }
    __syncthreads();
    float part = 0.f;
    for (int k = t; k < HID; k += 256) {
        const float4* wr = (const float4*)(fc1W + (size_t)k * HID);
        float acc = 0.f;
        #pragma unroll 4
        for (int mm = 0; mm < HID / 4; mm++) {
            float4 w4 = wr[mm];
            float4 c4 = *(const float4*)(comb + mm * 4);
            acc += w4.x * c4.x + w4.y * c4.y + w4.z * c4.z + w4.w * c4.w;
        }
        float hk = fmaxf(acc + fc1b[k], 0.f);
        part = fmaf(hk, fc2W[k], part);
    }
    red[t] = part; __syncthreads();
    for (int s = 128; s > 0; s >>= 1) { if (t < s) red[t] += red[t + s]; __syncthreads(); }
    if (t == 0) out[b] = red[0] + fc2b[0];
}

extern "C" void kernel_launch(void* const* d_in, const int* in_sizes, int n_in,
                              void* d_out, int out_size, void* d_ws, size_t ws_size,
                              hipStream_t stream) {
    const int*   topic_ids = (const int*)d_in[0];
    const int*   adj       = (const int*)d_in[1];
    const float* tm        = (const float*)d_in[2];
    const float* attr      = (const float*)d_in[3];
    const float* emb       = (const float*)d_in[4];
    const float* sW        = (const float*)d_in[5];
    const float* sb        = (const float*)d_in[6];
    const float* aW        = (const float*)d_in[7];
    const float* ab        = (const float*)d_in[8];
    const float* gW        = (const float*)d_in[9];   // (2,8,512,64)
    const float* ga        = (const float*)d_in[10];  // (2,8,128,1)
    const float* fc1W      = (const float*)d_in[11];
    const float* fc1b      = (const float*)d_in[12];
    const float* fc2W      = (const float*)d_in[13];
    const float* fc2b      = (const float*)d_in[14];
    float* out = (float*)d_out;

    char* p = (char*)d_ws;
    us* TWb    = (us*)p; p += sizeof(us) * (size_t)NB * NT * NT;        // 16.8 MB
    us* node0b = (us*)p; p += sizeof(us) * (size_t)NT * HID;            // 1 MB
    us* Wt     = (us*)p; p += sizeof(us) * (size_t)2 * NH * HD * HID;   // 1 MB
    us* Ht1    = (us*)p; p += sizeof(us) * (size_t)HID * NT;            // 1 MB
    us* node1b = (us*)p; p += sizeof(us) * (size_t)NB * NT * HID;       // 8 MB
    us* H2b    = (us*)p; p += sizeof(us) * (size_t)NB * NT * HID;       // 8 MB
    float* es1  = (float*)p; p += sizeof(float) * NH * NT;
    float* ed1  = (float*)p; p += sizeof(float) * NH * NT;
    float* es2  = (float*)p; p += sizeof(float) * NB * NH * NT;
    float* ed2  = (float*)p; p += sizeof(float) * NB * NH * NT;
    float* ppv  = (float*)p; p += sizeof(float) * NB * NH * 16 * HD;
    float* pl   = (float*)p; p += sizeof(float) * NB * NH * 16;
    float* part = (float*)p; p += sizeof(float) * 1024;

    kprep<<<1280, 256, 0, stream>>>(tm, part, emb, sW, sb, node0b, gW, Wt);
    kphase1<<<2176, 256, 0, stream>>>(tm, adj, part, TWb, node0b, Wt, ga, Ht1, es1, ed1);
    kattn1<<<dim3(16 * NB, NH), 256, 0, stream>>>(TWb, Ht1, es1, ed1, node1b);
    kgemm2<<<dim3(16 * NB, NH), 256, 0, stream>>>(node1b, Wt + (size_t)NH * HD * HID,
                                                  ga + NH * 2 * HD, H2b, es2, ed2);
    kattn2a<<<dim3(16, NH, NB), 256, 0, stream>>>(TWb, H2b, es2, ed2, topic_ids, ppv, pl);
    khead<<<NB, 256, 0, stream>>>(ppv, pl, attr, aW, ab, fc1W, fc1b, fc2W, fc2b, out);
}

// Round 9
// 234.927 us; speedup vs baseline: 1.1568x; 1.0203x over previous
//
#include <hip/hip_runtime.h>

#define NT 1024      // N_TOPICS
#define TD 128       // TOPIC_DIM
#define HID 512      // HIDDEN
#define NH 8         // N_HEADS
#define HD 64        // HEAD_DIM
#define NB 8         // BATCH

typedef unsigned short us;
typedef short bf16x8 __attribute__((ext_vector_type(8)));
typedef float f32x4 __attribute__((ext_vector_type(4)));

#define LOG2E 1.44269504f

__device__ __forceinline__ us f2bf(float x) {
    unsigned int u = __float_as_uint(x);
    return (us)((u + 0x7FFFu + ((u >> 16) & 1u)) >> 16);
}
__device__ __forceinline__ float bf2f(us s) {
    return __uint_as_float(((unsigned int)s) << 16);
}

// ============ kprep: kmax (0-1023) | node0 MFMA GEMM (1024-1151) | gW transpose (1152-1279)
__global__ __launch_bounds__(256) void kprep(const float* __restrict__ tm, float* __restrict__ part,
                                             const float* __restrict__ emb, const float* __restrict__ sW,
                                             const float* __restrict__ sb, us* __restrict__ node0b,
                                             const float* __restrict__ gW, us* __restrict__ Wt) {
    __shared__ __align__(16) float smf[8768];   // 35 KB shared by branches
    int bx = blockIdx.x, t = threadIdx.x;
    if (bx < 1024) {
        const float4* tm4 = (const float4*)tm;
        size_t base = (size_t)bx * 256 + t;
        float m = -1e30f;
        #pragma unroll
        for (int k = 0; k < 8; k++) {
            float4 v = tm4[base + (size_t)k * 262144];
            m = fmaxf(m, fmaxf(fmaxf(v.x, v.y), fmaxf(v.z, v.w)));
        }
        smf[t] = m; __syncthreads();
        for (int s = 128; s > 0; s >>= 1) { if (t < s) smf[t] = fmaxf(smf[t], smf[t + s]); __syncthreads(); }
        if (t == 0) part[bx] = smf[0];
    } else if (bx < 1152) {
        // node0 = emb @ sW^T + sb via MFMA. block: (iblk 16) x (oseg 8); K=128, one barrier.
        int g = bx - 1024; int iblk = g & 15, oseg = g >> 4;
        us* As = (us*)smf;              // [64][136]
        us* Bs = (us*)smf + 64 * 136;   // [64][136]
        const float4* esrc = (const float4*)(emb + (size_t)iblk * 64 * TD);
        const float4* wsrc = (const float4*)(sW + (size_t)oseg * 64 * TD);
        #pragma unroll
        for (int rep = 0; rep < 8; rep++) {
            int f = rep * 256 + t;
            int row = f >> 5, c4 = f & 31;
            float4 av = esrc[f];
            float4 bv = wsrc[f];
            us pa[4] = {f2bf(av.x), f2bf(av.y), f2bf(av.z), f2bf(av.w)};
            us pb[4] = {f2bf(bv.x), f2bf(bv.y), f2bf(bv.z), f2bf(bv.w)};
            *(uint2*)&As[row * 136 + c4 * 4] = *(uint2*)pa;
            *(uint2*)&Bs[row * 136 + c4 * 4] = *(uint2*)pb;
        }
        __syncthreads();
        int l = t & 63, w = t >> 6, m = l & 15, q = l >> 4;
        f32x4 acc[4];
        #pragma unroll
        for (int ot = 0; ot < 4; ot++) acc[ot] = (f32x4){0.f, 0.f, 0.f, 0.f};
        #pragma unroll
        for (int ks = 0; ks < 4; ks++) {
            bf16x8 a = *(const bf16x8*)&As[(w * 16 + m) * 136 + ks * 32 + q * 8];
            #pragma unroll
            for (int ot = 0; ot < 4; ot++) {
                bf16x8 b = *(const bf16x8*)&Bs[(ot * 16 + m) * 136 + ks * 32 + q * 8];
                acc[ot] = __builtin_amdgcn_mfma_f32_16x16x32_bf16(a, b, acc[ot], 0, 0, 0);
            }
        }
        #pragma unroll
        for (int ot = 0; ot < 4; ot++) {
            int col = oseg * 64 + ot * 16 + m;
            float sbv = sb[col];
            #pragma unroll
            for (int rr = 0; rr < 4; rr++) {
                int rowi = iblk * 64 + w * 16 + q * 4 + rr;
                node0b[(size_t)rowi * HID + col] = f2bf(acc[ot][rr] + sbv);
            }
        }
    } else {
        // Wt[lh][o][k] = bf16(gW[lh][k][o]) via LDS tile transpose
        int g = bx - 1152; int lh = g >> 3, kt = g & 7;
        float* tile = smf;   // [64][65]
        const float4* src = (const float4*)(gW + ((size_t)lh * HID + kt * 64) * HD);
        #pragma unroll
        for (int rep = 0; rep < 4; rep++) {
            int f = rep * 256 + t;
            float4 v = src[f];
            int row = f >> 4, col = (f & 15) * 4;
            float* d = tile + row * 65 + col;
            d[0] = v.x; d[1] = v.y; d[2] = v.z; d[3] = v.w;
        }
        __syncthreads();
        int o = t >> 2, ks = (t & 3) * 16;
        us pk[16];
        #pragma unroll
        for (int j = 0; j < 16; j++) pk[j] = f2bf(tile[(ks + j) * 65 + o]);
        us* dst = Wt + (size_t)lh * HD * HID + (size_t)o * HID + kt * 64 + ks;
        *(uint4*)dst = *(uint4*)pk;
        *(uint4*)(dst + 8) = *(uint4*)&pk[8];
    }
}

// ============ shared GEMM body: 64x64 tile, BK=64, dbuf, distance-2 global pipeline =====
__device__ __forceinline__ void gemm_body(const us* __restrict__ A, const us* __restrict__ W,
                                          const float* __restrict__ gav,
                                          us* __restrict__ outT, us* __restrict__ outR,
                                          float* __restrict__ esO, float* __restrict__ edO,
                                          int iblk, int b, int h, int t, us* sm) {
    us* As = sm;              // [2][64*72]
    us* Bs = sm + 2 * 4608;   // [2][64*72]
    int row = t >> 2, ks = t & 3;
    int l = t & 63, w = t >> 6, m = l & 15, q = l >> 4;
    size_t arow0 = (size_t)(b * NT + iblk * 64);
    const us* ar = A + (arow0 + row) * HID + ks * 16;
    const us* br = W + ((size_t)(h * HD + row)) * HID + ks * 16;
    f32x4 acc[4];
    #pragma unroll
    for (int ot = 0; ot < 4; ot++) acc[ot] = (f32x4){0.f, 0.f, 0.f, 0.f};
    {
        uint4 x0 = *(const uint4*)ar, x1 = *(const uint4*)(ar + 8);
        uint4 y0 = *(const uint4*)br, y1 = *(const uint4*)(br + 8);
        *(uint4*)&As[row * 72 + ks * 16] = x0; *(uint4*)&As[row * 72 + ks * 16 + 8] = x1;
        *(uint4*)&Bs[row * 72 + ks * 16] = y0; *(uint4*)&Bs[row * 72 + ks * 16 + 8] = y1;
    }
    uint4 a0 = *(const uint4*)(ar + 64), a1 = *(const uint4*)(ar + 72);
    uint4 b0 = *(const uint4*)(br + 64), b1 = *(const uint4*)(br + 72);
    for (int it = 0; it < 8; it++) {
        int cur = it & 1, nxt = cur ^ 1;
        uint4 na0, na1, nb0, nb1;
        if (it < 6) {
            int k0 = (it + 2) * 64;
            na0 = *(const uint4*)(ar + k0); na1 = *(const uint4*)(ar + k0 + 8);
            nb0 = *(const uint4*)(br + k0); nb1 = *(const uint4*)(br + k0 + 8);
        }
        __syncthreads();
        if (it < 7) {
            *(uint4*)&As[nxt * 4608 + row * 72 + ks * 16] = a0;
            *(uint4*)&As[nxt * 4608 + row * 72 + ks * 16 + 8] = a1;
            *(uint4*)&Bs[nxt * 4608 + row * 72 + ks * 16] = b0;
            *(uint4*)&Bs[nxt * 4608 + row * 72 + ks * 16 + 8] = b1;
        }
        const us* Ac = As + cur * 4608; const us* Bc = Bs + cur * 4608;
        #pragma unroll
        for (int kt = 0; kt < 2; kt++) {
            bf16x8 av = *(const bf16x8*)&Ac[(w * 16 + m) * 72 + kt * 32 + q * 8];
            #pragma unroll
            for (int ot = 0; ot < 4; ot++) {
                bf16x8 bv = *(const bf16x8*)&Bc[(ot * 16 + m) * 72 + kt * 32 + q * 8];
                acc[ot] = __builtin_amdgcn_mfma_f32_16x16x32_bf16(av, bv, acc[ot], 0, 0, 0);
            }
        }
        if (it < 6) { a0 = na0; a1 = na1; b0 = nb0; b1 = nb1; }
    }
    const float* gas = gav + h * 2 * HD;
    float gs[4], gd[4];
    #pragma unroll
    for (int ot = 0; ot < 4; ot++) { gs[ot] = gas[ot * 16 + m]; gd[ot] = gas[HD + ot * 16 + m]; }
    size_t ebase = ((size_t)b * NH + h) * NT + iblk * 64;
    #pragma unroll
    for (int rr = 0; rr < 4; rr++) {
        float s = 0.f, d = 0.f;
        #pragma unroll
        for (int ot = 0; ot < 4; ot++) { float v = acc[ot][rr]; s = fmaf(v, gs[ot], s); d = fmaf(v, gd[ot], d); }
        #pragma unroll
        for (int mask = 1; mask < 16; mask <<= 1) { s += __shfl_xor(s, mask); d += __shfl_xor(d, mask); }
        if (m == 0) {
            int rowi = w * 16 + q * 4 + rr;
            esO[ebase + rowi] = s;
            edO[ebase + rowi] = d;
        }
    }
    #pragma unroll
    for (int ot = 0; ot < 4; ot++) {
        int col = h * HD + ot * 16 + m;
        #pragma unroll
        for (int rr = 0; rr < 4; rr++) {
            int i_loc = w * 16 + q * 4 + rr;
            float v = acc[ot][rr];
            if (outT) outT[(size_t)col * NT + iblk * 64 + i_loc] = f2bf(v);
            if (outR) outR[(arow0 + i_loc) * HID + col] = f2bf(v);
        }
    }
}

// ============ kphase1: ktw (0-2047, tw*log2e or NaN) | layer-1 GEMM (2048-2175) =========
__global__ __launch_bounds__(256) void kphase1(const float* __restrict__ tm, const int* __restrict__ adj,
                                               const float* __restrict__ part, us* __restrict__ TWb,
                                               const us* __restrict__ node0b, const us* __restrict__ Wt,
                                               const float* __restrict__ ga, us* __restrict__ Ht1,
                                               float* __restrict__ es1, float* __restrict__ ed1) {
    __shared__ __align__(16) us sm[4 * 4608];
    int bx = blockIdx.x, t = threadIdx.x;
    if (bx < 2048) {
        float* red = (float*)sm;
        float m = fmaxf(fmaxf(part[t * 4], part[t * 4 + 1]), fmaxf(part[t * 4 + 2], part[t * 4 + 3]));
        red[t] = m; __syncthreads();
        for (int s = 128; s > 0; s >>= 1) { if (t < s) red[t] = fmaxf(red[t], red[t + s]); __syncthreads(); }
        float tmx = red[0];
        const float C = 0.1f * LOG2E;
        #pragma unroll
        for (int it = 0; it < 4; it++) {
            size_t idx = (((size_t)bx * 4 + it) * 256 + t) * 4;
            float4 tv = *(const float4*)(tm + idx);
            int4 av = *(const int4*)(adj + idx);
            float w0 = exp2f((tv.x - tmx) * C) * LOG2E;
            float w1 = exp2f((tv.y - tmx) * C) * LOG2E;
            float w2 = exp2f((tv.z - tmx) * C) * LOG2E;
            float w3 = exp2f((tv.w - tmx) * C) * LOG2E;
            unsigned int fa = av.x ? __float_as_uint(w0) : 0x7FC00000u;  // NaN when masked
            unsigned int fb = av.y ? __float_as_uint(w1) : 0x7FC00000u;
            unsigned int fc = av.z ? __float_as_uint(w2) : 0x7FC00000u;
            unsigned int fd = av.w ? __float_as_uint(w3) : 0x7FC00000u;
            uint2 pk;
            pk.x = __builtin_amdgcn_perm(fb, fa, 0x07060302);
            pk.y = __builtin_amdgcn_perm(fd, fc, 0x07060302);
            *(uint2*)&TWb[idx] = pk;
        }
    } else {
        int g = bx - 2048;
        gemm_body(node0b, Wt, ga, Ht1, nullptr, es1, ed1, g & 15, 0, g >> 4, t, sm);
    }
}

// ============ kedge: E1[h][i][j] = bf16(leaky(es1_i + ed1_j)), batch-invariant ==========
__global__ __launch_bounds__(256) void kedge(const float* __restrict__ es, const float* __restrict__ ed,
                                             us* __restrict__ E1) {
    int g = blockIdx.x;             // 2048: h = g>>8, 4 i-rows per block
    int h = g >> 8, i0 = (g & 255) << 2;
    int t = threadIdx.x;
    __shared__ float eds[NT];
    *(float4*)&eds[t * 4] = *(const float4*)&ed[h * NT + t * 4];
    __syncthreads();
    int j = t * 4;
    float4 e4 = *(const float4*)&eds[j];
    #pragma unroll
    for (int r = 0; r < 4; r++) {
        float esv = es[h * NT + i0 + r];
        float a = esv + e4.x; a = fmaxf(a, 0.2f * a);
        float bq = esv + e4.y; bq = fmaxf(bq, 0.2f * bq);
        float c = esv + e4.z; c = fmaxf(c, 0.2f * c);
        float d = esv + e4.w; d = fmaxf(d, 0.2f * d);
        uint2 pk;
        pk.x = __builtin_amdgcn_perm(__float_as_uint(bq), __float_as_uint(a), 0x07060302);
        pk.y = __builtin_amdgcn_perm(__float_as_uint(d), __float_as_uint(c), 0x07060302);
        *(uint2*)&E1[((size_t)(h * NT) + i0 + r) * NT + j] = pk;
    }
}

// ============ layer-2 GEMM =============================================================
__global__ __launch_bounds__(256) void kgemm2(const us* __restrict__ node1b, const us* __restrict__ Wt2,
                                              const float* __restrict__ ga2, us* __restrict__ H2b,
                                              float* __restrict__ es2, float* __restrict__ ed2) {
    __shared__ __align__(16) us sm[4 * 4608];
    int x = blockIdx.x;
    gemm_body(node1b, Wt2, ga2, nullptr, H2b, es2, ed2, x & 15, x >> 4, blockIdx.y, threadIdx.x, sm);
}

// ============ layer-1 attention: P = fmax(exp2(tw*E),0), NaN-masked, ones-MFMA denom ====
__device__ __forceinline__ void compute_p(uint4 T0, uint4 T1, uint4 E0, uint4 E1v,
                                          uint4& P01, uint4& P23) {
    union U { uint4 v; unsigned int w[4]; };
    U t0; t0.v = T0; U t1; t1.v = T1; U e0; e0.v = E0; U e1; e1.v = E1v;
    unsigned int pk[8];
    #pragma unroll
    for (int r = 0; r < 4; r++) {
        float twa = __uint_as_float(t0.w[r] << 16);
        float twb = __uint_as_float(t0.w[r] & 0xFFFF0000u);
        float Ea  = __uint_as_float(e0.w[r] << 16);
        float Eb  = __uint_as_float(e0.w[r] & 0xFFFF0000u);
        float pa = fmaxf(exp2f(twa * Ea), 0.f);   // NaN tw -> 0
        float pb = fmaxf(exp2f(twb * Eb), 0.f);
        pk[r] = __builtin_amdgcn_perm(__float_as_uint(pb), __float_as_uint(pa), 0x07060302);
    }
    #pragma unroll
    for (int r = 0; r < 4; r++) {
        float twa = __uint_as_float(t1.w[r] << 16);
        float twb = __uint_as_float(t1.w[r] & 0xFFFF0000u);
        float Ea  = __uint_as_float(e1.w[r] << 16);
        float Eb  = __uint_as_float(e1.w[r] & 0xFFFF0000u);
        float pa = fmaxf(exp2f(twa * Ea), 0.f);
        float pb = fmaxf(exp2f(twb * Eb), 0.f);
        pk[4 + r] = __builtin_amdgcn_perm(__float_as_uint(pb), __float_as_uint(pa), 0x07060302);
    }
    P01 = make_uint4(pk[0], pk[1], pk[2], pk[3]);
    P23 = make_uint4(pk[4], pk[5], pk[6], pk[7]);
}

__global__ __launch_bounds__(256) void kattn1(const us* __restrict__ TWb, const us* __restrict__ Ht,
                                              const us* __restrict__ E1, us* __restrict__ node1b) {
    int x = blockIdx.x; int iblk = x & 15; int b = x >> 4; int h = blockIdx.y;
    int t = threadIdx.x;
    __shared__ __align__(16) us Ps[2 * 4608];
    __shared__ __align__(16) us Hs[2 * 4608];
    __shared__ float invl_s[64];
    int i = t >> 2, js = t & 3;
    int l = t & 63, w = t >> 6, m = l & 15, q = l >> 4;
    const us* twrow = TWb + ((size_t)(b * NT) + iblk * 64 + i) * NT + js * 16;
    const us* erow  = E1 + ((size_t)(h * NT) + iblk * 64 + i) * NT + js * 16;
    const us* htrow = Ht + ((size_t)(h * HD) + i) * NT + js * 16;
    f32x4 acc[4];
    #pragma unroll
    for (int ot = 0; ot < 4; ot++) acc[ot] = (f32x4){0.f, 0.f, 0.f, 0.f};
    f32x4 acc1 = (f32x4){0.f, 0.f, 0.f, 0.f};       // ones-column: row sums of P
    short ov = (m == 0) ? (short)0x3F80 : (short)0;  // B[k][0]=1 else 0
    bf16x8 bones = {ov, ov, ov, ov, ov, ov, ov, ov};
    uint4 T0, T1, E0, E1r, Hh0, Hh1;
    // tile 0: load, compute, write buf0
    T0 = *(const uint4*)twrow; T1 = *(const uint4*)(twrow + 8);
    E0 = *(const uint4*)erow;  E1r = *(const uint4*)(erow + 8);
    Hh0 = *(const uint4*)htrow; Hh1 = *(const uint4*)(htrow + 8);
    {
        uint4 p01, p23;
        compute_p(T0, T1, E0, E1r, p01, p23);
        us* Pd = Ps + i * 72 + js * 16;
        us* Hd = Hs + i * 72 + js * 16;
        *(uint4*)Pd = p01; *(uint4*)(Pd + 8) = p23;
        *(uint4*)Hd = Hh0; *(uint4*)(Hd + 8) = Hh1;
    }
    // tile 1 loads
    T0 = *(const uint4*)(twrow + 64); T1 = *(const uint4*)(twrow + 72);
    E0 = *(const uint4*)(erow + 64);  E1r = *(const uint4*)(erow + 72);
    Hh0 = *(const uint4*)(htrow + 64); Hh1 = *(const uint4*)(htrow + 72);
    for (int it = 0; it < 16; it++) {
        int cur = it & 1, nxt = cur ^ 1;
        uint4 nT0, nT1, nE0, nE1, nH0, nH1;
        if (it < 14) {
            int j0 = (it + 2) * 64;
            nT0 = *(const uint4*)(twrow + j0); nT1 = *(const uint4*)(twrow + j0 + 8);
            nE0 = *(const uint4*)(erow + j0);  nE1 = *(const uint4*)(erow + j0 + 8);
            nH0 = *(const uint4*)(htrow + j0); nH1 = *(const uint4*)(htrow + j0 + 8);
        }
        uint4 p01, p23;
        if (it < 15) compute_p(T0, T1, E0, E1r, p01, p23);
        __syncthreads();
        if (it < 15) {
            us* Pd = Ps + nxt * 4608 + i * 72 + js * 16;
            us* Hd = Hs + nxt * 4608 + i * 72 + js * 16;
            *(uint4*)Pd = p01; *(uint4*)(Pd + 8) = p23;
            *(uint4*)Hd = Hh0; *(uint4*)(Hd + 8) = Hh1;
        }
        const us* Pc = Ps + cur * 4608; const us* Hc = Hs + cur * 4608;
        #pragma unroll
        for (int kt = 0; kt < 2; kt++) {
            bf16x8 av = *(const bf16x8*)&Pc[(w * 16 + m) * 72 + kt * 32 + q * 8];
            #pragma unroll
            for (int ot = 0; ot < 4; ot++) {
                bf16x8 bv = *(const bf16x8*)&Hc[(ot * 16 + m) * 72 + kt * 32 + q * 8];
                acc[ot] = __builtin_amdgcn_mfma_f32_16x16x32_bf16(av, bv, acc[ot], 0, 0, 0);
            }
            acc1 = __builtin_amdgcn_mfma_f32_16x16x32_bf16(av, bones, acc1, 0, 0, 0);
        }
        if (it < 14) { T0 = nT0; T1 = nT1; E0 = nE0; E1r = nE1; Hh0 = nH0; Hh1 = nH1; }
    }
    if (m == 0) {
        #pragma unroll
        for (int rr = 0; rr < 4; rr++) invl_s[w * 16 + q * 4 + rr] = 1.f / acc1[rr];
    }
    __syncthreads();
    #pragma unroll
    for (int ot = 0; ot < 4; ot++) {
        int col = h * HD + ot * 16 + m;
        #pragma unroll
        for (int rr = 0; rr < 4; rr++) {
            int i_loc = w * 16 + q * 4 + rr;
            float v = acc[ot][rr] * invl_s[i_loc];
            v = v > 0.f ? v : (__expf(v) - 1.f);  // ELU
            node1b[(size_t)(b * NT + iblk * 64 + i_loc) * HID + col] = f2bf(v);
        }
    }
}

// ============ layer-2 attention phase A: partial PV over 64-j slices (1024 blocks) ======
__global__ __launch_bounds__(256) void kattn2a(const us* __restrict__ TWb, const us* __restrict__ H2b,
                                               const float* __restrict__ es2, const float* __restrict__ ed2,
                                               const int* __restrict__ topic_ids,
                                               float* __restrict__ ppv, float* __restrict__ pl) {
    int js = blockIdx.x, h = blockIdx.y, b = blockIdx.z;
    int t = threadIdx.x;
    __shared__ float pls[64];
    __shared__ float red[256];
    int qi = topic_ids[b];
    if (t < 64) {
        int j = js * 64 + t;
        float esq = es2[((size_t)b * NH + h) * NT + qi];
        float tw = bf2f(TWb[((size_t)(b * NT) + qi) * NT + j]);  // tw*log2e or NaN
        float e = esq + ed2[((size_t)b * NH + h) * NT + j];
        e = fmaxf(e, 0.2f * e) * tw;
        float p = fmaxf(exp2f(e), 0.f);   // NaN -> 0
        pls[t] = p;
        float lsum = p;
        #pragma unroll
        for (int mask = 1; mask < 64; mask <<= 1) lsum += __shfl_xor(lsum, mask);
        if (t == 0) pl[((size_t)b * NH + h) * 16 + js] = lsum;
    }
    __syncthreads();
    int o = t & 63, jg = t >> 6;
    float acc = 0.f;
    const us* hb = H2b + ((size_t)(b * NT) + js * 64 + jg * 16) * HID + h * HD + o;
    #pragma unroll
    for (int jj = 0; jj < 16; jj++)
        acc = fmaf(pls[jg * 16 + jj], bf2f(hb[(size_t)jj * HID]), acc);
    red[t] = acc; __syncthreads();
    if (t < 64) {
        float pv = red[t] + red[t + 64] + red[t + 128] + red[t + 192];
        ppv[(((size_t)b * NH + h) * 16 + js) * HD + t] = pv;
    }
}

// ============ final head: reduce partials -> ELU -> combined -> fc1 relu -> fc2 =========
__global__ __launch_bounds__(256) void khead(const float* __restrict__ ppv, const float* __restrict__ pl,
                                             const float* __restrict__ attr,
                                             const float* __restrict__ aW, const float* __restrict__ ab,
                                             const float* __restrict__ fc1W, const float* __restrict__ fc1b,
                                             const float* __restrict__ fc2W, const float* __restrict__ fc2b,
                                             float* __restrict__ out) {
    int b = blockIdx.x, t = threadIdx.x;
    __shared__ float comb[HID];
    __shared__ float red[256];
    __shared__ float linv[NH];
    if (t < NH) {
        float lsum = 0.f;
        #pragma unroll
        for (int js = 0; js < 16; js++) lsum += pl[((size_t)b * NH + t) * 16 + js];
        linv[t] = 1.f / lsum;
    }
    __syncthreads();
    float av = attr[b];
    for (int k = t; k < HID; k += 256) {
        int h = k >> 6, o = k & 63;
        float pv = 0.f;
        #pragma unroll
        for (int js = 0; js < 16; js++) pv += ppv[(((size_t)b * NH + h) * 16 + js) * HD + o];
        float v = pv * linv[h];
        v = v > 0.f ? v : (__expf(v) - 1.f);  // ELU
        comb[k] = v + av * aW[k] + ab[k];
    }
    __syncthreads();
    float part = 0.f;
    for (int k = t; k < HID; k += 256) {
        const float4* wr = (const float4*)(fc1W + (size_t)k * HID);
        float acc = 0.f;
        #pragma unroll 4
        for (int mm = 0; mm < HID / 4; mm++) {
            float4 w4 = wr[mm];
            float4 c4 = *(const float4*)(comb + mm * 4);
            acc += w4.x * c4.x + w4.y * c4.y + w4.z * c4.z + w4.w * c4.w;
        }
        float hk = fmaxf(acc + fc1b[k], 0.f);
        part = fmaf(hk, fc2W[k], part);
    }
    red[t] = part; __syncthreads();
    for (int s = 128; s > 0; s >>= 1) { if (t < s) red[t] += red[t + s]; __syncthreads(); }
    if (t == 0) out[b] = red[0] + fc2b[0];
}

extern "C" void kernel_launch(void* const* d_in, const int* in_sizes, int n_in,
                              void* d_out, int out_size, void* d_ws, size_t ws_size,
                              hipStream_t stream) {
    const int*   topic_ids = (const int*)d_in[0];
    const int*   adj       = (const int*)d_in[1];
    const float* tm        = (const float*)d_in[2];
    const float* attr      = (const float*)d_in[3];
    const float* emb       = (const float*)d_in[4];
    const float* sW        = (const float*)d_in[5];
    const float* sb        = (const float*)d_in[6];
    const float* aW        = (const float*)d_in[7];
    const float* ab        = (const float*)d_in[8];
    const float* gW        = (const float*)d_in[9];   // (2,8,512,64)
    const float* ga        = (const float*)d_in[10];  // (2,8,128,1)
    const float* fc1W      = (const float*)d_in[11];
    const float* fc1b      = (const float*)d_in[12];
    const float* fc2W      = (const float*)d_in[13];
    const float* fc2b      = (const float*)d_in[14];
    float* out = (float*)d_out;

    char* p = (char*)d_ws;
    us* TWb    = (us*)p; p += sizeof(us) * (size_t)NB * NT * NT;        // 16.8 MB
    us* E1     = (us*)p; p += sizeof(us) * (size_t)NH * NT * NT;        // 16.8 MB
    us* node0b = (us*)p; p += sizeof(us) * (size_t)NT * HID;            // 1 MB
    us* Wt     = (us*)p; p += sizeof(us) * (size_t)2 * NH * HD * HID;   // 1 MB
    us* Ht1    = (us*)p; p += sizeof(us) * (size_t)HID * NT;            // 1 MB
    us* node1b = (us*)p; p += sizeof(us) * (size_t)NB * NT * HID;       // 8 MB
    us* H2b    = (us*)p; p += sizeof(us) * (size_t)NB * NT * HID;       // 8 MB
    float* es1  = (float*)p; p += sizeof(float) * NH * NT;
    float* ed1  = (float*)p; p += sizeof(float) * NH * NT;
    float* es2  = (float*)p; p += sizeof(float) * NB * NH * NT;
    float* ed2  = (float*)p; p += sizeof(float) * NB * NH * NT;
    float* ppv  = (float*)p; p += sizeof(float) * NB * NH * 16 * HD;
    float* pl   = (float*)p; p += sizeof(float) * NB * NH * 16;
    float* part = (float*)p; p += sizeof(float) * 1024;

    kprep<<<1280, 256, 0, stream>>>(tm, part, emb, sW, sb, node0b, gW, Wt);
    kphase1<<<2176, 256, 0, stream>>>(tm, adj, part, TWb, node0b, Wt, ga, Ht1, es1, ed1);
    kedge<<<2048, 256, 0, stream>>>(es1, ed1, E1);
    kattn1<<<dim3(16 * NB, NH), 256, 0, stream>>>(TWb, Ht1, E1, node1b);
    kgemm2<<<dim3(16 * NB, NH), 256, 0, stream>>>(node1b, Wt + (size_t)NH * HD * HID,
                                                  ga + NH * 2 * HD, H2b, es2, ed2);
    kattn2a<<<dim3(16, NH, NB), 256, 0, stream>>>(TWb, H2b, es2, ed2, topic_ids, ppv, pl);
    khead<<<NB, 256, 0, stream>>>(ppv, pl, attr, aW, ab, fc1W, fc1b, fc2W, fc2b, out);
}

// Round 10
// 203.146 us; speedup vs baseline: 1.3378x; 1.1564x over previous
//
#include <hip/hip_runtime.h>

#define NT 1024      // N_TOPICS
#define TD 128       // TOPIC_DIM
#define HID 512      // HIDDEN
#define NH 8         // N_HEADS
#define HD 64        // HEAD_DIM
#define NB 8         // BATCH

typedef unsigned short us;
typedef short bf16x8 __attribute__((ext_vector_type(8)));
typedef float f32x4 __attribute__((ext_vector_type(4)));

#define LOG2E 1.44269504f

__device__ __forceinline__ us f2bf(float x) {
    unsigned int u = __float_as_uint(x);
    return (us)((u + 0x7FFFu + ((u >> 16) & 1u)) >> 16);
}
__device__ __forceinline__ float bf2f(us s) {
    return __uint_as_float(((unsigned int)s) << 16);
}

// ============ kprep: kmax (0-1023) | node0 MFMA GEMM (1024-1151) | gW transpose (1152-1279)
//              block 1152 also initializes out[b] = fc2b[0] for khead2's atomics
__global__ __launch_bounds__(256) void kprep(const float* __restrict__ tm, float* __restrict__ part,
                                             const float* __restrict__ emb, const float* __restrict__ sW,
                                             const float* __restrict__ sb, us* __restrict__ node0b,
                                             const float* __restrict__ gW, us* __restrict__ Wt,
                                             const float* __restrict__ fc2b, float* __restrict__ out) {
    __shared__ __align__(16) float smf[8768];   // 35 KB shared by branches
    int bx = blockIdx.x, t = threadIdx.x;
    if (bx < 1024) {
        const float4* tm4 = (const float4*)tm;
        size_t base = (size_t)bx * 256 + t;
        float m = -1e30f;
        #pragma unroll
        for (int k = 0; k < 8; k++) {
            float4 v = tm4[base + (size_t)k * 262144];
            m = fmaxf(m, fmaxf(fmaxf(v.x, v.y), fmaxf(v.z, v.w)));
        }
        smf[t] = m; __syncthreads();
        for (int s = 128; s > 0; s >>= 1) { if (t < s) smf[t] = fmaxf(smf[t], smf[t + s]); __syncthreads(); }
        if (t == 0) part[bx] = smf[0];
    } else if (bx < 1152) {
        // node0 = emb @ sW^T + sb via MFMA. block: (iblk 16) x (oseg 8); K=128, one barrier.
        int g = bx - 1024; int iblk = g & 15, oseg = g >> 4;
        us* As = (us*)smf;              // [64][136]
        us* Bs = (us*)smf + 64 * 136;   // [64][136]
        const float4* esrc = (const float4*)(emb + (size_t)iblk * 64 * TD);
        const float4* wsrc = (const float4*)(sW + (size_t)oseg * 64 * TD);
        #pragma unroll
        for (int rep = 0; rep < 8; rep++) {
            int f = rep * 256 + t;
            int row = f >> 5, c4 = f & 31;
            float4 av = esrc[f];
            float4 bv = wsrc[f];
            us pa[4] = {f2bf(av.x), f2bf(av.y), f2bf(av.z), f2bf(av.w)};
            us pb[4] = {f2bf(bv.x), f2bf(bv.y), f2bf(bv.z), f2bf(bv.w)};
            *(uint2*)&As[row * 136 + c4 * 4] = *(uint2*)pa;
            *(uint2*)&Bs[row * 136 + c4 * 4] = *(uint2*)pb;
        }
        __syncthreads();
        int l = t & 63, w = t >> 6, m = l & 15, q = l >> 4;
        f32x4 acc[4];
        #pragma unroll
        for (int ot = 0; ot < 4; ot++) acc[ot] = (f32x4){0.f, 0.f, 0.f, 0.f};
        #pragma unroll
        for (int ks = 0; ks < 4; ks++) {
            bf16x8 a = *(const bf16x8*)&As[(w * 16 + m) * 136 + ks * 32 + q * 8];
            #pragma unroll
            for (int ot = 0; ot < 4; ot++) {
                bf16x8 b = *(const bf16x8*)&Bs[(ot * 16 + m) * 136 + ks * 32 + q * 8];
                acc[ot] = __builtin_amdgcn_mfma_f32_16x16x32_bf16(a, b, acc[ot], 0, 0, 0);
            }
        }
        #pragma unroll
        for (int ot = 0; ot < 4; ot++) {
            int col = oseg * 64 + ot * 16 + m;
            float sbv = sb[col];
            #pragma unroll
            for (int rr = 0; rr < 4; rr++) {
                int rowi = iblk * 64 + w * 16 + q * 4 + rr;
                node0b[(size_t)rowi * HID + col] = f2bf(acc[ot][rr] + sbv);
            }
        }
    } else {
        // Wt[lh][o][k] = bf16(gW[lh][k][o]) via LDS tile transpose
        int g = bx - 1152; int lh = g >> 3, kt = g & 7;
        if (g == 0 && t < NB) out[t] = fc2b[0];   // init for khead2 atomics
        float* tile = smf;   // [64][65]
        const float4* src = (const float4*)(gW + ((size_t)lh * HID + kt * 64) * HD);
        #pragma unroll
        for (int rep = 0; rep < 4; rep++) {
            int f = rep * 256 + t;
            float4 v = src[f];
            int row = f >> 4, col = (f & 15) * 4;
            float* d = tile + row * 65 + col;
            d[0] = v.x; d[1] = v.y; d[2] = v.z; d[3] = v.w;
        }
        __syncthreads();
        int o = t >> 2, ks = (t & 3) * 16;
        us pk[16];
        #pragma unroll
        for (int j = 0; j < 16; j++) pk[j] = f2bf(tile[(ks + j) * 65 + o]);
        us* dst = Wt + (size_t)lh * HD * HID + (size_t)o * HID + kt * 64 + ks;
        *(uint4*)dst = *(uint4*)pk;
        *(uint4*)(dst + 8) = *(uint4*)&pk[8];
    }
}

// ============ shared GEMM body: 64x64 tile, BK=64, dbuf, distance-2 global pipeline =====
__device__ __forceinline__ void gemm_body(const us* __restrict__ A, const us* __restrict__ W,
                                          const float* __restrict__ gav,
                                          us* __restrict__ outT, us* __restrict__ outR,
                                          float* __restrict__ esO, float* __restrict__ edO,
                                          int iblk, int b, int h, int t, us* sm) {
    us* As = sm;              // [2][64*72]
    us* Bs = sm + 2 * 4608;   // [2][64*72]
    int row = t >> 2, ks = t & 3;
    int l = t & 63, w = t >> 6, m = l & 15, q = l >> 4;
    size_t arow0 = (size_t)(b * NT + iblk * 64);
    const us* ar = A + (arow0 + row) * HID + ks * 16;
    const us* br = W + ((size_t)(h * HD + row)) * HID + ks * 16;
    f32x4 acc[4];
    #pragma unroll
    for (int ot = 0; ot < 4; ot++) acc[ot] = (f32x4){0.f, 0.f, 0.f, 0.f};
    {
        uint4 x0 = *(const uint4*)ar, x1 = *(const uint4*)(ar + 8);
        uint4 y0 = *(const uint4*)br, y1 = *(const uint4*)(br + 8);
        *(uint4*)&As[row * 72 + ks * 16] = x0; *(uint4*)&As[row * 72 + ks * 16 + 8] = x1;
        *(uint4*)&Bs[row * 72 + ks * 16] = y0; *(uint4*)&Bs[row * 72 + ks * 16 + 8] = y1;
    }
    uint4 a0 = *(const uint4*)(ar + 64), a1 = *(const uint4*)(ar + 72);
    uint4 b0 = *(const uint4*)(br + 64), b1 = *(const uint4*)(br + 72);
    for (int it = 0; it < 8; it++) {
        int cur = it & 1, nxt = cur ^ 1;
        uint4 na0, na1, nb0, nb1;
        if (it < 6) {
            int k0 = (it + 2) * 64;
            na0 = *(const uint4*)(ar + k0); na1 = *(const uint4*)(ar + k0 + 8);
            nb0 = *(const uint4*)(br + k0); nb1 = *(const uint4*)(br + k0 + 8);
        }
        __syncthreads();
        if (it < 7) {
            *(uint4*)&As[nxt * 4608 + row * 72 + ks * 16] = a0;
            *(uint4*)&As[nxt * 4608 + row * 72 + ks * 16 + 8] = a1;
            *(uint4*)&Bs[nxt * 4608 + row * 72 + ks * 16] = b0;
            *(uint4*)&Bs[nxt * 4608 + row * 72 + ks * 16 + 8] = b1;
        }
        const us* Ac = As + cur * 4608; const us* Bc = Bs + cur * 4608;
        #pragma unroll
        for (int kt = 0; kt < 2; kt++) {
            bf16x8 av = *(const bf16x8*)&Ac[(w * 16 + m) * 72 + kt * 32 + q * 8];
            #pragma unroll
            for (int ot = 0; ot < 4; ot++) {
                bf16x8 bv = *(const bf16x8*)&Bc[(ot * 16 + m) * 72 + kt * 32 + q * 8];
                acc[ot] = __builtin_amdgcn_mfma_f32_16x16x32_bf16(av, bv, acc[ot], 0, 0, 0);
            }
        }
        if (it < 6) { a0 = na0; a1 = na1; b0 = nb0; b1 = nb1; }
    }
    const float* gas = gav + h * 2 * HD;
    float gs[4], gd[4];
    #pragma unroll
    for (int ot = 0; ot < 4; ot++) { gs[ot] = gas[ot * 16 + m]; gd[ot] = gas[HD + ot * 16 + m]; }
    size_t ebase = ((size_t)b * NH + h) * NT + iblk * 64;
    #pragma unroll
    for (int rr = 0; rr < 4; rr++) {
        float s = 0.f, d = 0.f;
        #pragma unroll
        for (int ot = 0; ot < 4; ot++) { float v = acc[ot][rr]; s = fmaf(v, gs[ot], s); d = fmaf(v, gd[ot], d); }
        #pragma unroll
        for (int mask = 1; mask < 16; mask <<= 1) { s += __shfl_xor(s, mask); d += __shfl_xor(d, mask); }
        if (m == 0) {
            int rowi = w * 16 + q * 4 + rr;
            esO[ebase + rowi] = s;
            edO[ebase + rowi] = d;
        }
    }
    #pragma unroll
    for (int ot = 0; ot < 4; ot++) {
        int col = h * HD + ot * 16 + m;
        #pragma unroll
        for (int rr = 0; rr < 4; rr++) {
            int i_loc = w * 16 + q * 4 + rr;
            float v = acc[ot][rr];
            if (outT) outT[(size_t)col * NT + iblk * 64 + i_loc] = f2bf(v);
            if (outR) outR[(arow0 + i_loc) * HID + col] = f2bf(v);
        }
    }
}

// ============ kphase1: ktw (0-2047, tw*log2e or NaN) | layer-1 GEMM (2048-2175) =========
__global__ __launch_bounds__(256) void kphase1(const float* __restrict__ tm, const int* __restrict__ adj,
                                               const float* __restrict__ part, us* __restrict__ TWb,
                                               const us* __restrict__ node0b, const us* __restrict__ Wt,
                                               const float* __restrict__ ga, us* __restrict__ Ht1,
                                               float* __restrict__ es1, float* __restrict__ ed1) {
    __shared__ __align__(16) us sm[4 * 4608];
    int bx = blockIdx.x, t = threadIdx.x;
    if (bx < 2048) {
        float* red = (float*)sm;
        float m = fmaxf(fmaxf(part[t * 4], part[t * 4 + 1]), fmaxf(part[t * 4 + 2], part[t * 4 + 3]));
        red[t] = m; __syncthreads();
        for (int s = 128; s > 0; s >>= 1) { if (t < s) red[t] = fmaxf(red[t], red[t + s]); __syncthreads(); }
        float tmx = red[0];
        const float C = 0.1f * LOG2E;
        #pragma unroll
        for (int it = 0; it < 4; it++) {
            size_t idx = (((size_t)bx * 4 + it) * 256 + t) * 4;
            float4 tv = *(const float4*)(tm + idx);
            int4 av = *(const int4*)(adj + idx);
            float w0 = exp2f((tv.x - tmx) * C) * LOG2E;
            float w1 = exp2f((tv.y - tmx) * C) * LOG2E;
            float w2 = exp2f((tv.z - tmx) * C) * LOG2E;
            float w3 = exp2f((tv.w - tmx) * C) * LOG2E;
            unsigned int fa = av.x ? __float_as_uint(w0) : 0x7FC00000u;  // NaN when masked
            unsigned int fb = av.y ? __float_as_uint(w1) : 0x7FC00000u;
            unsigned int fc = av.z ? __float_as_uint(w2) : 0x7FC00000u;
            unsigned int fd = av.w ? __float_as_uint(w3) : 0x7FC00000u;
            uint2 pk;
            pk.x = __builtin_amdgcn_perm(fb, fa, 0x07060302);
            pk.y = __builtin_amdgcn_perm(fd, fc, 0x07060302);
            *(uint2*)&TWb[idx] = pk;
        }
    } else {
        int g = bx - 2048;
        gemm_body(node0b, Wt, ga, Ht1, nullptr, es1, ed1, g & 15, 0, g >> 4, t, sm);
    }
}

// ============ kedge: E1[h][i][j] = bf16(leaky(es1_i + ed1_j)), batch-invariant ==========
__global__ __launch_bounds__(256) void kedge(const float* __restrict__ es, const float* __restrict__ ed,
                                             us* __restrict__ E1) {
    int g = blockIdx.x;             // 2048: h = g>>8, 4 i-rows per block
    int h = g >> 8, i0 = (g & 255) << 2;
    int t = threadIdx.x;
    __shared__ float eds[NT];
    *(float4*)&eds[t * 4] = *(const float4*)&ed[h * NT + t * 4];
    __syncthreads();
    int j = t * 4;
    float4 e4 = *(const float4*)&eds[j];
    #pragma unroll
    for (int r = 0; r < 4; r++) {
        float esv = es[h * NT + i0 + r];
        float a = esv + e4.x; a = fmaxf(a, 0.2f * a);
        float bq = esv + e4.y; bq = fmaxf(bq, 0.2f * bq);
        float c = esv + e4.z; c = fmaxf(c, 0.2f * c);
        float d = esv + e4.w; d = fmaxf(d, 0.2f * d);
        uint2 pk;
        pk.x = __builtin_amdgcn_perm(__float_as_uint(bq), __float_as_uint(a), 0x07060302);
        pk.y = __builtin_amdgcn_perm(__float_as_uint(d), __float_as_uint(c), 0x07060302);
        *(uint2*)&E1[((size_t)(h * NT) + i0 + r) * NT + j] = pk;
    }
}

// ============ layer-2 GEMM =============================================================
__global__ __launch_bounds__(256) void kgemm2(const us* __restrict__ node1b, const us* __restrict__ Wt2,
                                              const float* __restrict__ ga2, us* __restrict__ H2b,
                                              float* __restrict__ es2, float* __restrict__ ed2) {
    __shared__ __align__(16) us sm[4 * 4608];
    int x = blockIdx.x;
    gemm_body(node1b, Wt2, ga2, nullptr, H2b, es2, ed2, x & 15, x >> 4, blockIdx.y, threadIdx.x, sm);
}

// ============ layer-1 attention: P = fmax(exp2(tw*E),0), NaN-masked, ones-MFMA denom ====
__device__ __forceinline__ void compute_p(uint4 T0, uint4 T1, uint4 E0, uint4 E1v,
                                          uint4& P01, uint4& P23) {
    union U { uint4 v; unsigned int w[4]; };
    U t0; t0.v = T0; U t1; t1.v = T1; U e0; e0.v = E0; U e1; e1.v = E1v;
    unsigned int pk[8];
    #pragma unroll
    for (int r = 0; r < 4; r++) {
        float twa = __uint_as_float(t0.w[r] << 16);
        float twb = __uint_as_float(t0.w[r] & 0xFFFF0000u);
        float Ea  = __uint_as_float(e0.w[r] << 16);
        float Eb  = __uint_as_float(e0.w[r] & 0xFFFF0000u);
        float pa = fmaxf(exp2f(twa * Ea), 0.f);   // NaN tw -> 0
        float pb = fmaxf(exp2f(twb * Eb), 0.f);
        pk[r] = __builtin_amdgcn_perm(__float_as_uint(pb), __float_as_uint(pa), 0x07060302);
    }
    #pragma unroll
    for (int r = 0; r < 4; r++) {
        float twa = __uint_as_float(t1.w[r] << 16);
        float twb = __uint_as_float(t1.w[r] & 0xFFFF0000u);
        float Ea  = __uint_as_float(e1.w[r] << 16);
        float Eb  = __uint_as_float(e1.w[r] & 0xFFFF0000u);
        float pa = fmaxf(exp2f(twa * Ea), 0.f);
        float pb = fmaxf(exp2f(twb * Eb), 0.f);
        pk[4 + r] = __builtin_amdgcn_perm(__float_as_uint(pb), __float_as_uint(pa), 0x07060302);
    }
    P01 = make_uint4(pk[0], pk[1], pk[2], pk[3]);
    P23 = make_uint4(pk[4], pk[5], pk[6], pk[7]);
}

__global__ __launch_bounds__(256) void kattn1(const us* __restrict__ TWb, const us* __restrict__ Ht,
                                              const us* __restrict__ E1, us* __restrict__ node1b) {
    int x = blockIdx.x; int iblk = x & 15; int b = x >> 4; int h = blockIdx.y;
    int t = threadIdx.x;
    __shared__ __align__(16) us Ps[2 * 4608];
    __shared__ __align__(16) us Hs[2 * 4608];
    __shared__ float invl_s[64];
    int i = t >> 2, js = t & 3;
    int l = t & 63, w = t >> 6, m = l & 15, q = l >> 4;
    const us* twrow = TWb + ((size_t)(b * NT) + iblk * 64 + i) * NT + js * 16;
    const us* erow  = E1 + ((size_t)(h * NT) + iblk * 64 + i) * NT + js * 16;
    const us* htrow = Ht + ((size_t)(h * HD) + i) * NT + js * 16;
    f32x4 acc[4];
    #pragma unroll
    for (int ot = 0; ot < 4; ot++) acc[ot] = (f32x4){0.f, 0.f, 0.f, 0.f};
    f32x4 acc1 = (f32x4){0.f, 0.f, 0.f, 0.f};       // ones-column: row sums of P
    short ov = (m == 0) ? (short)0x3F80 : (short)0;  // B[k][0]=1 else 0
    bf16x8 bones = {ov, ov, ov, ov, ov, ov, ov, ov};
    uint4 T0, T1, E0, E1r, Hh0, Hh1;
    T0 = *(const uint4*)twrow; T1 = *(const uint4*)(twrow + 8);
    E0 = *(const uint4*)erow;  E1r = *(const uint4*)(erow + 8);
    Hh0 = *(const uint4*)htrow; Hh1 = *(const uint4*)(htrow + 8);
    {
        uint4 p01, p23;
        compute_p(T0, T1, E0, E1r, p01, p23);
        us* Pd = Ps + i * 72 + js * 16;
        us* Hd = Hs + i * 72 + js * 16;
        *(uint4*)Pd = p01; *(uint4*)(Pd + 8) = p23;
        *(uint4*)Hd = Hh0; *(uint4*)(Hd + 8) = Hh1;
    }
    T0 = *(const uint4*)(twrow + 64); T1 = *(const uint4*)(twrow + 72);
    E0 = *(const uint4*)(erow + 64);  E1r = *(const uint4*)(erow + 72);
    Hh0 = *(const uint4*)(htrow + 64); Hh1 = *(const uint4*)(htrow + 72);
    for (int it = 0; it < 16; it++) {
        int cur = it & 1, nxt = cur ^ 1;
        uint4 nT0, nT1, nE0, nE1, nH0, nH1;
        if (it < 14) {
            int j0 = (it + 2) * 64;
            nT0 = *(const uint4*)(twrow + j0); nT1 = *(const uint4*)(twrow + j0 + 8);
            nE0 = *(const uint4*)(erow + j0);  nE1 = *(const uint4*)(erow + j0 + 8);
            nH0 = *(const uint4*)(htrow + j0); nH1 = *(const uint4*)(htrow + j0 + 8);
        }
        uint4 p01, p23;
        if (it < 15) compute_p(T0, T1, E0, E1r, p01, p23);
        __syncthreads();
        if (it < 15) {
            us* Pd = Ps + nxt * 4608 + i * 72 + js * 16;
            us* Hd = Hs + nxt * 4608 + i * 72 + js * 16;
            *(uint4*)Pd = p01; *(uint4*)(Pd + 8) = p23;
            *(uint4*)Hd = Hh0; *(uint4*)(Hd + 8) = Hh1;
        }
        const us* Pc = Ps + cur * 4608; const us* Hc = Hs + cur * 4608;
        #pragma unroll
        for (int kt = 0; kt < 2; kt++) {
            bf16x8 av = *(const bf16x8*)&Pc[(w * 16 + m) * 72 + kt * 32 + q * 8];
            #pragma unroll
            for (int ot = 0; ot < 4; ot++) {
                bf16x8 bv = *(const bf16x8*)&Hc[(ot * 16 + m) * 72 + kt * 32 + q * 8];
                acc[ot] = __builtin_amdgcn_mfma_f32_16x16x32_bf16(av, bv, acc[ot], 0, 0, 0);
            }
            acc1 = __builtin_amdgcn_mfma_f32_16x16x32_bf16(av, bones, acc1, 0, 0, 0);
        }
        if (it < 14) { T0 = nT0; T1 = nT1; E0 = nE0; E1r = nE1; Hh0 = nH0; Hh1 = nH1; }
    }
    if (m == 0) {
        #pragma unroll
        for (int rr = 0; rr < 4; rr++) invl_s[w * 16 + q * 4 + rr] = 1.f / acc1[rr];
    }
    __syncthreads();
    #pragma unroll
    for (int ot = 0; ot < 4; ot++) {
        int col = h * HD + ot * 16 + m;
        #pragma unroll
        for (int rr = 0; rr < 4; rr++) {
            int i_loc = w * 16 + q * 4 + rr;
            float v = acc[ot][rr] * invl_s[i_loc];
            v = v > 0.f ? v : (__expf(v) - 1.f);  // ELU
            node1b[(size_t)(b * NT + iblk * 64 + i_loc) * HID + col] = f2bf(v);
        }
    }
}

// ============ layer-2 attention phase A: partial PV over 64-j slices (1024 blocks) ======
__global__ __launch_bounds__(256) void kattn2a(const us* __restrict__ TWb, const us* __restrict__ H2b,
                                               const float* __restrict__ es2, const float* __restrict__ ed2,
                                               const int* __restrict__ topic_ids,
                                               float* __restrict__ ppv, float* __restrict__ pl) {
    int js = blockIdx.x, h = blockIdx.y, b = blockIdx.z;
    int t = threadIdx.x;
    __shared__ float pls[64];
    __shared__ float red[256];
    int qi = topic_ids[b];
    if (t < 64) {
        int j = js * 64 + t;
        float esq = es2[((size_t)b * NH + h) * NT + qi];
        float tw = bf2f(TWb[((size_t)(b * NT) + qi) * NT + j]);  // tw*log2e or NaN
        float e = esq + ed2[((size_t)b * NH + h) * NT + j];
        e = fmaxf(e, 0.2f * e) * tw;
        float p = fmaxf(exp2f(e), 0.f);   // NaN -> 0
        pls[t] = p;
        float lsum = p;
        #pragma unroll
        for (int mask = 1; mask < 64; mask <<= 1) lsum += __shfl_xor(lsum, mask);
        if (t == 0) pl[((size_t)b * NH + h) * 16 + js] = lsum;
    }
    __syncthreads();
    int o = t & 63, jg = t >> 6;
    float acc = 0.f;
    const us* hb = H2b + ((size_t)(b * NT) + js * 64 + jg * 16) * HID + h * HD + o;
    #pragma unroll
    for (int jj = 0; jj < 16; jj++)
        acc = fmaf(pls[jg * 16 + jj], bf2f(hb[(size_t)jj * HID]), acc);
    red[t] = acc; __syncthreads();
    if (t < 64) {
        float pv = red[t] + red[t + 64] + red[t + 128] + red[t + 192];
        ppv[(((size_t)b * NH + h) * 16 + js) * HD + t] = pv;
    }
}

// ============ khead2: 256 blocks (kseg 32 x b 8); atomicAdd partials into out[b] ========
__global__ __launch_bounds__(256) void khead2(const float* __restrict__ ppv, const float* __restrict__ pl,
                                              const float* __restrict__ attr,
                                              const float* __restrict__ aW, const float* __restrict__ ab,
                                              const float* __restrict__ fc1W, const float* __restrict__ fc1b,
                                              const float* __restrict__ fc2W, float* __restrict__ out) {
    int kseg = blockIdx.x, b = blockIdx.y;
    int t = threadIdx.x;
    __shared__ float comb[HID];
    __shared__ float linv[NH];
    __shared__ float r2[256];
    if (t < NH) {
        float lsum = 0.f;
        #pragma unroll
        for (int js = 0; js < 16; js++) lsum += pl[((size_t)b * NH + t) * 16 + js];
        linv[t] = 1.f / lsum;
    }
    __syncthreads();
    float av = attr[b];
    for (int k = t; k < HID; k += 256) {
        int h = k >> 6, o = k & 63;
        float pv = 0.f;
        #pragma unroll
        for (int js = 0; js < 16; js++) pv += ppv[(((size_t)b * NH + h) * 16 + js) * HD + o];
        float v = pv * linv[h];
        v = v > 0.f ? v : (__expf(v) - 1.f);  // ELU
        comb[k] = v + av * aW[k] + ab[k];
    }
    __syncthreads();
    // 16 fc1 rows per block; 16 threads per row, coalesced scalar reads
    int kk = kseg * 16 + (t >> 4);
    int j = t & 15;
    const float* row = fc1W + (size_t)kk * HID;
    float acc = 0.f;
    #pragma unroll 8
    for (int mi = 0; mi < 32; mi++) {
        int idx = mi * 16 + j;
        acc = fmaf(comb[idx], row[idx], acc);
    }
    #pragma unroll
    for (int mask = 1; mask < 16; mask <<= 1) acc += __shfl_xor(acc, mask);
    float partv = 0.f;
    if (j == 0) {
        float hk = fmaxf(acc + fc1b[kk], 0.f);
        partv = hk * fc2W[kk];
    }
    r2[t] = partv; __syncthreads();
    for (int s = 128; s > 0; s >>= 1) { if (t < s) r2[t] += r2[t + s]; __syncthreads(); }
    if (t == 0) atomicAdd(&out[b], r2[0]);
}

extern "C" void kernel_launch(void* const* d_in, const int* in_sizes, int n_in,
                              void* d_out, int out_size, void* d_ws, size_t ws_size,
                              hipStream_t stream) {
    const int*   topic_ids = (const int*)d_in[0];
    const int*   adj       = (const int*)d_in[1];
    const float* tm        = (const float*)d_in[2];
    const float* attr      = (const float*)d_in[3];
    const float* emb       = (const float*)d_in[4];
    const float* sW        = (const float*)d_in[5];
    const float* sb        = (const float*)d_in[6];
    const float* aW        = (const float*)d_in[7];
    const float* ab        = (const float*)d_in[8];
    const float* gW        = (const float*)d_in[9];   // (2,8,512,64)
    const float* ga        = (const float*)d_in[10];  // (2,8,128,1)
    const float* fc1W      = (const float*)d_in[11];
    const float* fc1b      = (const float*)d_in[12];
    const float* fc2W      = (const float*)d_in[13];
    const float* fc2b      = (const float*)d_in[14];
    float* out = (float*)d_out;

    char* p = (char*)d_ws;
    us* TWb    = (us*)p; p += sizeof(us) * (size_t)NB * NT * NT;        // 16.8 MB
    us* E1     = (us*)p; p += sizeof(us) * (size_t)NH * NT * NT;        // 16.8 MB
    us* node0b = (us*)p; p += sizeof(us) * (size_t)NT * HID;            // 1 MB
    us* Wt     = (us*)p; p += sizeof(us) * (size_t)2 * NH * HD * HID;   // 1 MB
    us* Ht1    = (us*)p; p += sizeof(us) * (size_t)HID * NT;            // 1 MB
    us* node1b = (us*)p; p += sizeof(us) * (size_t)NB * NT * HID;       // 8 MB
    us* H2b    = (us*)p; p += sizeof(us) * (size_t)NB * NT * HID;       // 8 MB
    float* es1  = (float*)p; p += sizeof(float) * NH * NT;
    float* ed1  = (float*)p; p += sizeof(float) * NH * NT;
    float* es2  = (float*)p; p += sizeof(float) * NB * NH * NT;
    float* ed2  = (float*)p; p += sizeof(float) * NB * NH * NT;
    float* ppv  = (float*)p; p += sizeof(float) * NB * NH * 16 * HD;
    float* pl   = (float*)p; p += sizeof(float) * NB * NH * 16;
    float* part = (float*)p; p += sizeof(float) * 1024;

    kprep<<<1280, 256, 0, stream>>>(tm, part, emb, sW, sb, node0b, gW, Wt, fc2b, out);
    kphase1<<<2176, 256, 0, stream>>>(tm, adj, part, TWb, node0b, Wt, ga, Ht1, es1, ed1);
    kedge<<<2048, 256, 0, stream>>>(es1, ed1, E1);
    kattn1<<<dim3(16 * NB, NH), 256, 0, stream>>>(TWb, Ht1, E1, node1b);
    kgemm2<<<dim3(16 * NB, NH), 256, 0, stream>>>(node1b, Wt + (size_t)NH * HD * HID,
                                                  ga + NH * 2 * HD, H2b, es2, ed2);
    kattn2a<<<dim3(16, NH, NB), 256, 0, stream>>>(TWb, H2b, es2, ed2, topic_ids, ppv, pl);
    khead2<<<dim3(32, NB), 256, 0, stream>>>(ppv, pl, attr, aW, ab, fc1W, fc1b, fc2W, out);
}